// Round 3
// baseline (4135.895 us; speedup 1.0000x reference)
//
#include <hip/hip_runtime.h>
#include <stdint.h>

#define B_ 16
#define N_ 4096
#define D_ 64
#define S_ 1024
#define K_ 32
#define M_ (B_*S_*K_)   /* 524288 */
#define NQ_ (B_*S_)     /* 16384 */
#define EPS_ 1e-5f

static __device__ __forceinline__ float bf2f(uint16_t u){
  union{uint32_t i; float f;} v; v.i = ((uint32_t)u) << 16; return v.f;
}
static __device__ __forceinline__ uint16_t f2bf(float f){
  union{uint32_t i; float f;} v; v.f = f;
  uint32_t u = v.i;
  uint32_t r = (u + 0x7FFFu + ((u >> 16) & 1u)) >> 16;   // RNE, finite inputs
  return (uint16_t)r;
}

// ---------------------------------------------------------------------------
// 0) Zero the global stats accumulators (ws is poisoned 0xAA before launch).
// ---------------------------------------------------------------------------
__global__ __launch_bounds__(256) void zero_stats_kernel(float* __restrict__ s){
  s[blockIdx.x * 256 + threadIdx.x] = 0.0f;   // grid 2 -> 512 floats
}

// ---------------------------------------------------------------------------
// 1) Farthest point sampling: one block per batch, 1024 threads, 4 pts/thread
//    in registers. Argmax carries the winning point's coords through the
//    shuffle tree so NO dynamic register indexing is needed.
//    fp32, exact-order, no FMA -- verified bit-matching vs reference (round 2).
// ---------------------------------------------------------------------------
__global__ __launch_bounds__(1024) void fps_kernel(const float* __restrict__ xyz,
                                                   float* __restrict__ out_newxyz){
  const int b = blockIdx.x;
  const int tid = threadIdx.x;
  const float* X = xyz + (size_t)b * N_ * 3;
  float px[4], py[4], pz[4], dist[4];
#pragma unroll
  for(int t = 0; t < 4; ++t){
    int p = tid + t * 1024;
    px[t] = X[p*3 + 0]; py[t] = X[p*3 + 1]; pz[t] = X[p*3 + 2];
    dist[t] = 1e10f;
  }
  __shared__ float smv[17]; __shared__ int smi[17];
  __shared__ float smx[17], smy[17], smz[17];
  float cx = X[0], cy = X[1], cz = X[2];       // reference: idx[0] = 0
  if(tid == 0){
    float* o = out_newxyz + (size_t)b * S_ * 3;
    o[0] = cx; o[1] = cy; o[2] = cz;
  }
  for(int it = 1; it < S_; ++it){
    float best = -1.0f; int bi = 0; float bx = 0.f, by = 0.f, bz = 0.f;
#pragma unroll
    for(int t = 0; t < 4; ++t){
      float d;
      {
#pragma clang fp contract(off)
        float dx = px[t] - cx, dy = py[t] - cy, dz = pz[t] - cz;
        d = dx*dx + dy*dy + dz*dz;   // match reference: plain mul/add, left-to-right
      }
      float nd = fminf(dist[t], d);
      dist[t] = nd;
      if(nd > best){ best = nd; bi = tid + t*1024; bx = px[t]; by = py[t]; bz = pz[t]; }
    }
    // wave argmax, lowest index on tie (jnp.argmax semantics)
#pragma unroll
    for(int off = 1; off < 64; off <<= 1){
      float ov = __shfl_xor(best, off, 64); int oi = __shfl_xor(bi, off, 64);
      float ox = __shfl_xor(bx, off, 64), oy = __shfl_xor(by, off, 64), oz = __shfl_xor(bz, off, 64);
      bool take = (ov > best) || (ov == best && oi < bi);
      if(take){ best = ov; bi = oi; bx = ox; by = oy; bz = oz; }
    }
    if((tid & 63) == 0){
      int w = tid >> 6;
      smv[w] = best; smi[w] = bi; smx[w] = bx; smy[w] = by; smz[w] = bz;
    }
    __syncthreads();
    if(tid < 64){
      int l = tid & 15;     // 4x duplicated slots; tie-break by idx is harmless
      best = smv[l]; bi = smi[l]; bx = smx[l]; by = smy[l]; bz = smz[l];
#pragma unroll
      for(int off = 1; off < 64; off <<= 1){
        float ov = __shfl_xor(best, off, 64); int oi = __shfl_xor(bi, off, 64);
        float ox = __shfl_xor(bx, off, 64), oy = __shfl_xor(by, off, 64), oz = __shfl_xor(bz, off, 64);
        bool take = (ov > best) || (ov == best && oi < bi);
        if(take){ best = ov; bi = oi; bx = ox; by = oy; bz = oz; }
      }
      if(tid == 0){
        smv[16] = best; smi[16] = bi; smx[16] = bx; smy[16] = by; smz[16] = bz;
        float* o = out_newxyz + ((size_t)b * S_ + it) * 3;
        o[0] = bx; o[1] = by; o[2] = bz;
      }
    }
    __syncthreads();
    cx = smx[16]; cy = smy[16]; cz = smz[16];
  }
}

// ---------------------------------------------------------------------------
// 2) Ball query: one wave per query. First 32 indices (ascending) with
//    sq <= r^2, pad with first.
//    sq computed in FP64: bit-identical to a numpy float64 reference
//    (fp32 products are exact in fp64; 3-term sums sequential in both),
//    eliminating boundary-membership flips vs that reference.
// ---------------------------------------------------------------------------
__global__ __launch_bounds__(256) void ballq_kernel(const float* __restrict__ xyz,
                                                    const float* __restrict__ newxyz,
                                                    int* __restrict__ gidx){
  const int wslot = threadIdx.x >> 6;
  const int lane  = threadIdx.x & 63;
  const int q = blockIdx.x * 4 + wslot;        // [0, NQ_)
  const int b = q >> 10;
  const float* X = xyz + (size_t)b * N_ * 3;
  const double R2D = 0.2 * 0.2;                // == Python 0.2**2 (0.04000000000000001)
  double nx, ny, nz, sa;
  {
    const float* NP = newxyz + (size_t)q * 3;
    nx = (double)NP[0]; ny = (double)NP[1]; nz = (double)NP[2];
    sa = nx*nx + ny*ny + nz*nz;
  }
  __shared__ int sidx[4][K_];
  int count = 0;
  for(int base = 0; base < N_; base += 64){
    int p = base + lane;
    double pxv = (double)X[p*3 + 0], pyv = (double)X[p*3 + 1], pzv = (double)X[p*3 + 2];
    double sb = pxv*pxv + pyv*pyv + pzv*pzv;
    double dt = nx*pxv + ny*pyv + nz*pzv;
    double sq = sa + sb - 2.0 * dt;            // ((sa+sb) - 2*dot) like reference
    bool inb = !(sq > R2D);
    unsigned long long mask = __ballot(inb);
    int pos = count + __popcll(mask & ((1ull << lane) - 1ull));
    if(inb && pos < K_) sidx[wslot][pos] = p;
    count += (int)__popcll(mask);
    if(count >= K_) break;                     // count is wave-uniform
  }
  __syncthreads();
  int nvalid = count < K_ ? count : K_;
  if(lane < K_){
    int first = sidx[wslot][0];               // count >= 1 always (self-point, sq == 0)
    int v = (lane < nvalid) ? sidx[wslot][lane] : first;
    gidx[(size_t)q * K_ + lane] = v;
  }
}

// ---------------------------------------------------------------------------
// 3) Layer 1: gather + concat + GEMM (67 -> 64) + bias. Writes y1 bf16 (64,M)
//    and accumulates per-channel sum/sumsq (fused, fp32) into gstats0.
// ---------------------------------------------------------------------------
__global__ __launch_bounds__(256) void layer1_kernel(const float* __restrict__ xyz,
                                                     const float* __restrict__ pts,
                                                     const float* __restrict__ newxyz,
                                                     const int* __restrict__ gidx,
                                                     const float* __restrict__ w,
                                                     const float* __restrict__ bias,
                                                     uint16_t* __restrict__ y,
                                                     float* __restrict__ gstats){
  __shared__ float sm_sum[64*33];
  __shared__ float sm_sq [64*33];
  const int tid = threadIdx.x;
  for(int i = tid; i < 64*33; i += 256){ sm_sum[i] = 0.f; sm_sq[i] = 0.f; }
  __syncthreads();

  const int m = blockIdx.x * 256 + tid;
  const int bs = m >> 5;
  const int b  = bs >> 10;
  const int j  = gidx[m];
  float x[67];
  {
    const float* nxp = newxyz + (size_t)bs * 3;
    const float* pp  = xyz + ((size_t)b * N_ + j) * 3;
    x[0] = pp[0] - nxp[0]; x[1] = pp[1] - nxp[1]; x[2] = pp[2] - nxp[2];
  }
  {
    const float4* pr = (const float4*)(pts + ((size_t)b * N_ + j) * D_);
#pragma unroll
    for(int c4 = 0; c4 < 16; ++c4){
      float4 v = pr[c4];
      x[3 + c4*4 + 0] = v.x; x[3 + c4*4 + 1] = v.y;
      x[3 + c4*4 + 2] = v.z; x[3 + c4*4 + 3] = v.w;
    }
  }
  const int col = tid & 31;
  for(int o = 0; o < 64; ++o){
    float acc = bias[o];
#pragma unroll
    for(int c = 0; c < 67; ++c) acc = fmaf(w[o*67 + c], x[c], acc);  // w uniform -> s_load
    y[(size_t)o * M_ + m] = f2bf(acc);
    atomicAdd(&sm_sum[o*33 + col], acc);        // ds_add_f32, 2 lanes/bank
    atomicAdd(&sm_sq [o*33 + col], acc*acc);
  }
  __syncthreads();
  if(tid < 64){
    float s = 0.f;
#pragma unroll
    for(int c = 0; c < 32; ++c) s += sm_sum[tid*33 + c];
    atomicAdd(&gstats[tid], s);
  } else if(tid < 128){
    int o = tid - 64; float s = 0.f;
#pragma unroll
    for(int c = 0; c < 32; ++c) s += sm_sq[o*33 + c];
    atomicAdd(&gstats[64 + o], s);
  }
}

// ---------------------------------------------------------------------------
// 4) Layer 2 (stats only): BN0+ReLU on y1, GEMM (64->64)+bias, accumulate
//    per-channel sum/sumsq into gstats1. No activation tensor is written;
//    layer 3 recomputes the identical values (deterministic same-order fma).
// ---------------------------------------------------------------------------
__global__ __launch_bounds__(256) void layer2_stats_kernel(const uint16_t* __restrict__ y1,
                                                           const float* __restrict__ gstats0,
                                                           const float* __restrict__ g,
                                                           const float* __restrict__ bt,
                                                           const float* __restrict__ w,
                                                           const float* __restrict__ bias,
                                                           float* __restrict__ gstats1){
  __shared__ float la[64], lb[64];
  __shared__ float sm_sum[64*33];
  __shared__ float sm_sq [64*33];
  const int tid = threadIdx.x;
  for(int i = tid; i < 64*33; i += 256){ sm_sum[i] = 0.f; sm_sq[i] = 0.f; }
  if(tid < 64){
    float mean = gstats0[tid] * (1.0f / M_);
    float var  = gstats0[64 + tid] * (1.0f / M_) - mean * mean;
    float inv  = 1.0f / sqrtf(var + EPS_);
    float a = g[tid] * inv;
    la[tid] = a; lb[tid] = bt[tid] - mean * a;
  }
  __syncthreads();

  const int m = blockIdx.x * 256 + tid;
  float h[64];
#pragma unroll
  for(int c = 0; c < 64; ++c){
    float v = bf2f(y1[(size_t)c * M_ + m]);
    h[c] = fmaxf(la[c] * v + lb[c], 0.0f);
  }
  const int col = tid & 31;
  for(int o = 0; o < 64; ++o){
    float acc = bias[o];
#pragma unroll
    for(int c = 0; c < 64; ++c) acc = fmaf(w[o*64 + c], h[c], acc);
    atomicAdd(&sm_sum[o*33 + col], acc);
    atomicAdd(&sm_sq [o*33 + col], acc*acc);
  }
  __syncthreads();
  if(tid < 64){
    float s = 0.f;
#pragma unroll
    for(int c = 0; c < 32; ++c) s += sm_sum[tid*33 + c];
    atomicAdd(&gstats1[tid], s);
  } else if(tid < 128){
    int o = tid - 64; float s = 0.f;
#pragma unroll
    for(int c = 0; c < 32; ++c) s += sm_sq[o*33 + c];
    atomicAdd(&gstats1[64 + o], s);
  }
}

// ---------------------------------------------------------------------------
// 5) Layer 3: recompute L2 (BN0+ReLU -> GEMM), BN1+ReLU, L3 GEMM (64->128),
//    fused stats2 + max/min over the K=32 group (shuffle tree).
//    maxk/mink are fp32 in (bs, o) layout == final output layout.
// ---------------------------------------------------------------------------
__global__ __launch_bounds__(256) void layer3_kernel(const uint16_t* __restrict__ y1,
                                                     const float* __restrict__ gstats0,
                                                     const float* __restrict__ g0,
                                                     const float* __restrict__ bt0,
                                                     const float* __restrict__ w1,
                                                     const float* __restrict__ b1,
                                                     const float* __restrict__ gstats1,
                                                     const float* __restrict__ g1,
                                                     const float* __restrict__ bt1,
                                                     const float* __restrict__ w2,
                                                     const float* __restrict__ b2,
                                                     float* __restrict__ gstats2,
                                                     float* __restrict__ maxk,
                                                     float* __restrict__ mink){
  __shared__ float la0[64], lb0[64], la1[64], lb1[64];
  __shared__ float sm_sum[128*33];
  __shared__ float sm_sq [128*33];
  const int tid = threadIdx.x;
  for(int i = tid; i < 128*33; i += 256){ sm_sum[i] = 0.f; sm_sq[i] = 0.f; }
  if(tid < 64){
    float mean = gstats0[tid] * (1.0f / M_);
    float var  = gstats0[64 + tid] * (1.0f / M_) - mean * mean;
    float inv  = 1.0f / sqrtf(var + EPS_);
    float a = g0[tid] * inv;
    la0[tid] = a; lb0[tid] = bt0[tid] - mean * a;
  } else if(tid < 128){
    int o = tid - 64;
    float mean = gstats1[o] * (1.0f / M_);
    float var  = gstats1[64 + o] * (1.0f / M_) - mean * mean;
    float inv  = 1.0f / sqrtf(var + EPS_);
    float a = g1[o] * inv;
    la1[o] = a; lb1[o] = bt1[o] - mean * a;
  }
  __syncthreads();

  const int m = blockIdx.x * 256 + tid;
  const int bs = m >> 5;
  float h1[64];
#pragma unroll
  for(int c = 0; c < 64; ++c){
    float v = bf2f(y1[(size_t)c * M_ + m]);
    h1[c] = fmaxf(la0[c] * v + lb0[c], 0.0f);
  }
  float h2[64];
  for(int o = 0; o < 64; ++o){
    float acc = b1[o];
#pragma unroll
    for(int c = 0; c < 64; ++c) acc = fmaf(w1[o*64 + c], h1[c], acc);
    h2[o] = fmaxf(la1[o] * acc + lb1[o], 0.0f);
  }
  const int col = tid & 31;
  for(int o = 0; o < 128; ++o){
    float acc = b2[o];
#pragma unroll
    for(int c = 0; c < 64; ++c) acc = fmaf(w2[o*64 + c], h2[c], acc);
    atomicAdd(&sm_sum[o*33 + col], acc);
    atomicAdd(&sm_sq [o*33 + col], acc*acc);
    float mx = acc, mn = acc;
#pragma unroll
    for(int off = 1; off < 32; off <<= 1){       // stays within the 32-lane k-group
      mx = fmaxf(mx, __shfl_xor(mx, off, 64));
      mn = fminf(mn, __shfl_xor(mn, off, 64));
    }
    if((tid & 31) == 0){
      maxk[(size_t)bs * 128 + o] = mx;
      mink[(size_t)bs * 128 + o] = mn;
    }
  }
  __syncthreads();
  if(tid < 128){
    float s = 0.f;
#pragma unroll
    for(int c = 0; c < 32; ++c) s += sm_sum[tid*33 + c];
    atomicAdd(&gstats2[tid], s);
  } else {
    int o = tid - 128; float s = 0.f;
#pragma unroll
    for(int c = 0; c < 32; ++c) s += sm_sq[o*33 + c];
    atomicAdd(&gstats2[128 + o], s);
  }
}

// ---------------------------------------------------------------------------
// 6) Final: BN2+ReLU applied to max/min endpoints (max_k relu(a*v+b) =
//    max(relu(a*mx+b), relu(a*mn+b)) for either sign of a). Fully coalesced.
// ---------------------------------------------------------------------------
__global__ __launch_bounds__(256) void final_kernel(const float* __restrict__ maxk,
                                                    const float* __restrict__ mink,
                                                    const float* __restrict__ gstats2,
                                                    const float* __restrict__ g,
                                                    const float* __restrict__ bt,
                                                    float* __restrict__ out_np){
  const int gid = blockIdx.x * 256 + threadIdx.x;   // == bs*128 + o
  const int o = gid & 127;
  float mean = gstats2[o] * (1.0f / M_);
  float var  = gstats2[128 + o] * (1.0f / M_) - mean * mean;
  float inv  = 1.0f / sqrtf(var + EPS_);
  float a = g[o] * inv;
  float b = bt[o] - mean * a;
  float mx = maxk[gid], mn = mink[gid];
  out_np[gid] = fmaxf(fmaxf(a * mx + b, 0.0f), fmaxf(a * mn + b, 0.0f));
}

// ---------------------------------------------------------------------------
extern "C" void kernel_launch(void* const* d_in, const int* in_sizes, int n_in,
                              void* d_out, int out_size, void* d_ws, size_t ws_size,
                              hipStream_t stream){
  (void)in_sizes; (void)n_in; (void)out_size;
  const float* xyz = (const float*)d_in[0];
  const float* pts = (const float*)d_in[1];
  const float* w0 = (const float*)d_in[2];  const float* b0  = (const float*)d_in[3];
  const float* g0 = (const float*)d_in[4];  const float* bt0 = (const float*)d_in[5];
  const float* w1 = (const float*)d_in[6];  const float* b1  = (const float*)d_in[7];
  const float* g1 = (const float*)d_in[8];  const float* bt1 = (const float*)d_in[9];
  const float* w2 = (const float*)d_in[10]; const float* b2  = (const float*)d_in[11];
  const float* g2 = (const float*)d_in[12]; const float* bt2 = (const float*)d_in[13];

  float* out    = (float*)d_out;
  float* newxyz = out;                       // (B,S,3)
  float* newpts = out + (size_t)B_ * S_ * 3; // (B,S,128)

  // Workspace layout (total ~82.1 MB):
  const size_t off_gidx  = 0;
  const size_t off_stats = off_gidx  + (size_t)M_ * 4;
  const size_t off_maxk  = off_stats + 65536;
  const size_t off_mink  = off_maxk  + (size_t)NQ_ * 128 * 4;
  const size_t off_y1    = off_mink  + (size_t)NQ_ * 128 * 4;
  const size_t need      = off_y1    + (size_t)M_ * 64 * 2;
  if(ws_size < need) return;   // graceful failure instead of a device fault

  char* ws = (char*)d_ws;
  int*      gidx   = (int*)     (ws + off_gidx);
  float*    gstats = (float*)   (ws + off_stats);
  float*    maxk   = (float*)   (ws + off_maxk);
  float*    mink   = (float*)   (ws + off_mink);
  uint16_t* y1     = (uint16_t*)(ws + off_y1);

  zero_stats_kernel<<<2, 256, 0, stream>>>(gstats);
  fps_kernel  <<<B_, 1024, 0, stream>>>(xyz, newxyz);
  ballq_kernel<<<NQ_ / 4, 256, 0, stream>>>(xyz, newxyz, gidx);

  layer1_kernel      <<<M_ / 256, 256, 0, stream>>>(xyz, pts, newxyz, gidx, w0, b0, y1, gstats);
  layer2_stats_kernel<<<M_ / 256, 256, 0, stream>>>(y1, gstats, g0, bt0, w1, b1, gstats + 128);
  layer3_kernel      <<<M_ / 256, 256, 0, stream>>>(y1, gstats, g0, bt0, w1, b1,
                                                    gstats + 128, g1, bt1, w2, b2,
                                                    gstats + 256, maxk, mink);
  final_kernel<<<(NQ_ * 128) / 256, 256, 0, stream>>>(maxk, mink, gstats + 256, g2, bt2, newpts);
}

// Round 4
// 3295.184 us; speedup vs baseline: 1.2551x; 1.2551x over previous
//
#include <hip/hip_runtime.h>
#include <stdint.h>

#define B_ 16
#define N_ 4096
#define D_ 64
#define S_ 1024
#define K_ 32
#define M_ (B_*S_*K_)   /* 524288 */
#define NQ_ (B_*S_)     /* 16384 */
#define EPS_ 1e-5f

static __device__ __forceinline__ float bf2f(uint16_t u){
  union{uint32_t i; float f;} v; v.i = ((uint32_t)u) << 16; return v.f;
}
static __device__ __forceinline__ uint16_t f2bf(float f){
  union{uint32_t i; float f;} v; v.f = f;
  uint32_t u = v.i;
  uint32_t r = (u + 0x7FFFu + ((u >> 16) & 1u)) >> 16;   // RNE, finite inputs
  return (uint16_t)r;
}

// ---------------------------------------------------------------------------
// 0) Zero the global stats accumulators (ws is poisoned 0xAA before launch).
// ---------------------------------------------------------------------------
__global__ __launch_bounds__(256) void zero_stats_kernel(float* __restrict__ s){
  s[blockIdx.x * 256 + threadIdx.x] = 0.0f;   // grid 2 -> 512 floats
}

// ---------------------------------------------------------------------------
// 1) Farthest point sampling. One block/batch, 1024 threads, 4 pts/thread in
//    registers. Per iteration: thread-local argmax (float cmp, ascending idx
//    -> first-max), pack (dist,idx) into u64 key = (bits<<32)|~idx (positive
//    float bits are monotone; ~idx -> lowest index wins ties, matching
//    jnp.argmax), 6-level u64 shuffle tree, ONE barrier, then all 16 waves
//    redundantly reduce the 16 per-wave keys from LDS (broadcast reads).
//    Winner coords re-read from an LDS copy of xyz (broadcast). Distance
//    math is bit-identical to the verified round-3 kernel.
// ---------------------------------------------------------------------------
__global__ __launch_bounds__(1024) void fps_kernel(const float* __restrict__ xyz,
                                                   float* __restrict__ out_newxyz){
  const int b = blockIdx.x;
  const int tid = threadIdx.x;
  const float* X = xyz + (size_t)b * N_ * 3;
  __shared__ float sx[N_], sy[N_], sz[N_];          // 48 KB coord cache
  __shared__ unsigned long long slots[2][16];       // parity double-buffered
  float px[4], py[4], pz[4], dist[4];
#pragma unroll
  for(int t = 0; t < 4; ++t){
    int p = tid + t * 1024;
    px[t] = X[p*3 + 0]; py[t] = X[p*3 + 1]; pz[t] = X[p*3 + 2];
    dist[t] = 1e10f;
    sx[p] = px[t]; sy[p] = py[t]; sz[p] = pz[t];
  }
  __syncthreads();
  int far = 0;                                      // reference: idx[0] = 0
  for(int it = 0; it < S_; ++it){
    float cx = sx[far], cy = sy[far], cz = sz[far]; // broadcast LDS reads
    if(tid == 0){
      float* o = out_newxyz + ((size_t)b * S_ + it) * 3;
      o[0] = cx; o[1] = cy; o[2] = cz;
    }
    if(it == S_ - 1) break;
    float bestd = -1.0f; int bestp = 0;
#pragma unroll
    for(int t = 0; t < 4; ++t){
      float d;
      {
#pragma clang fp contract(off)
        float dx = px[t] - cx, dy = py[t] - cy, dz = pz[t] - cz;
        d = dx*dx + dy*dy + dz*dz;   // match reference: plain mul/add, left-to-right
      }
      float nd = fminf(dist[t], d);
      dist[t] = nd;
      if(nd > bestd){ bestd = nd; bestp = tid + t*1024; }  // ascending idx -> first max
    }
    unsigned long long key = ((unsigned long long)__float_as_uint(bestd) << 32)
                           | (unsigned long long)(uint32_t)(~bestp);
#pragma unroll
    for(int off = 1; off < 64; off <<= 1){
      unsigned long long ok = __shfl_xor(key, off, 64);
      if(ok > key) key = ok;
    }
    const int par = it & 1;
    if((tid & 63) == 0) slots[par][tid >> 6] = key;
    __syncthreads();
    unsigned long long bk = slots[par][0];
#pragma unroll
    for(int w = 1; w < 16; ++w){
      unsigned long long ok = slots[par][w];
      if(ok > bk) bk = ok;
    }
    far = (int)(~(uint32_t)bk);                     // uniform across block
  }
}

// ---------------------------------------------------------------------------
// 2) Ball query: one wave per query. First 32 indices (ascending) with
//    sq <= r^2, pad with first. FP64 sq: bit-identical to the numpy float64
//    reference (verified round 3).
// ---------------------------------------------------------------------------
__global__ __launch_bounds__(256) void ballq_kernel(const float* __restrict__ xyz,
                                                    const float* __restrict__ newxyz,
                                                    int* __restrict__ gidx){
  const int wslot = threadIdx.x >> 6;
  const int lane  = threadIdx.x & 63;
  const int q = blockIdx.x * 4 + wslot;        // [0, NQ_)
  const int b = q >> 10;
  const float* X = xyz + (size_t)b * N_ * 3;
  const double R2D = 0.2 * 0.2;                // == Python 0.2**2
  double nx, ny, nz, sa;
  {
    const float* NP = newxyz + (size_t)q * 3;
    nx = (double)NP[0]; ny = (double)NP[1]; nz = (double)NP[2];
    sa = nx*nx + ny*ny + nz*nz;
  }
  __shared__ int sidx[4][K_];
  int count = 0;
  for(int base = 0; base < N_; base += 64){
    int p = base + lane;
    double pxv = (double)X[p*3 + 0], pyv = (double)X[p*3 + 1], pzv = (double)X[p*3 + 2];
    double sb = pxv*pxv + pyv*pyv + pzv*pzv;
    double dt = nx*pxv + ny*pyv + nz*pzv;
    double sq = sa + sb - 2.0 * dt;            // ((sa+sb) - 2*dot) like reference
    bool inb = !(sq > R2D);
    unsigned long long mask = __ballot(inb);
    int pos = count + __popcll(mask & ((1ull << lane) - 1ull));
    if(inb && pos < K_) sidx[wslot][pos] = p;
    count += (int)__popcll(mask);
    if(count >= K_) break;                     // count is wave-uniform
  }
  __syncthreads();
  int nvalid = count < K_ ? count : K_;
  if(lane < K_){
    int first = sidx[wslot][0];               // count >= 1 always (self-point, sq == 0)
    int v = (lane < nvalid) ? sidx[wslot][lane] : first;
    gidx[(size_t)q * K_ + lane] = v;
  }
}

// ---------------------------------------------------------------------------
// 3) Layer 1: gather + concat + GEMM (67 -> 64) + bias. Writes y1 bf16 (64,M)
//    and accumulates per-channel sum/sumsq (fused, fp32) into gstats0.
// ---------------------------------------------------------------------------
__global__ __launch_bounds__(256) void layer1_kernel(const float* __restrict__ xyz,
                                                     const float* __restrict__ pts,
                                                     const float* __restrict__ newxyz,
                                                     const int* __restrict__ gidx,
                                                     const float* __restrict__ w,
                                                     const float* __restrict__ bias,
                                                     uint16_t* __restrict__ y,
                                                     float* __restrict__ gstats){
  __shared__ float sm_sum[64*33];
  __shared__ float sm_sq [64*33];
  const int tid = threadIdx.x;
  for(int i = tid; i < 64*33; i += 256){ sm_sum[i] = 0.f; sm_sq[i] = 0.f; }
  __syncthreads();

  const int m = blockIdx.x * 256 + tid;
  const int bs = m >> 5;
  const int b  = bs >> 10;
  const int j  = gidx[m];
  float x[67];
  {
    const float* nxp = newxyz + (size_t)bs * 3;
    const float* pp  = xyz + ((size_t)b * N_ + j) * 3;
    x[0] = pp[0] - nxp[0]; x[1] = pp[1] - nxp[1]; x[2] = pp[2] - nxp[2];
  }
  {
    const float4* pr = (const float4*)(pts + ((size_t)b * N_ + j) * D_);
#pragma unroll
    for(int c4 = 0; c4 < 16; ++c4){
      float4 v = pr[c4];
      x[3 + c4*4 + 0] = v.x; x[3 + c4*4 + 1] = v.y;
      x[3 + c4*4 + 2] = v.z; x[3 + c4*4 + 3] = v.w;
    }
  }
  const int col = tid & 31;
  for(int o = 0; o < 64; ++o){
    float acc = bias[o];
#pragma unroll
    for(int c = 0; c < 67; ++c) acc = fmaf(w[o*67 + c], x[c], acc);  // w uniform -> s_load
    y[(size_t)o * M_ + m] = f2bf(acc);
    atomicAdd(&sm_sum[o*33 + col], acc);        // ds_add_f32, 2 lanes/bank
    atomicAdd(&sm_sq [o*33 + col], acc*acc);
  }
  __syncthreads();
  if(tid < 64){
    float s = 0.f;
#pragma unroll
    for(int c = 0; c < 32; ++c) s += sm_sum[tid*33 + c];
    atomicAdd(&gstats[tid], s);
  } else if(tid < 128){
    int o = tid - 64; float s = 0.f;
#pragma unroll
    for(int c = 0; c < 32; ++c) s += sm_sq[o*33 + c];
    atomicAdd(&gstats[64 + o], s);
  }
}

// ---------------------------------------------------------------------------
// 4) Layer 2 (stats only): BN0+ReLU on y1, GEMM (64->64)+bias, accumulate
//    per-channel sum/sumsq into gstats1. No activation tensor is written;
//    layer 3 recomputes the identical values (deterministic same-order fma).
// ---------------------------------------------------------------------------
__global__ __launch_bounds__(256) void layer2_stats_kernel(const uint16_t* __restrict__ y1,
                                                           const float* __restrict__ gstats0,
                                                           const float* __restrict__ g,
                                                           const float* __restrict__ bt,
                                                           const float* __restrict__ w,
                                                           const float* __restrict__ bias,
                                                           float* __restrict__ gstats1){
  __shared__ float la[64], lb[64];
  __shared__ float sm_sum[64*33];
  __shared__ float sm_sq [64*33];
  const int tid = threadIdx.x;
  for(int i = tid; i < 64*33; i += 256){ sm_sum[i] = 0.f; sm_sq[i] = 0.f; }
  if(tid < 64){
    float mean = gstats0[tid] * (1.0f / M_);
    float var  = gstats0[64 + tid] * (1.0f / M_) - mean * mean;
    float inv  = 1.0f / sqrtf(var + EPS_);
    float a = g[tid] * inv;
    la[tid] = a; lb[tid] = bt[tid] - mean * a;
  }
  __syncthreads();

  const int m = blockIdx.x * 256 + tid;
  float h[64];
#pragma unroll
  for(int c = 0; c < 64; ++c){
    float v = bf2f(y1[(size_t)c * M_ + m]);
    h[c] = fmaxf(la[c] * v + lb[c], 0.0f);
  }
  const int col = tid & 31;
  for(int o = 0; o < 64; ++o){
    float acc = bias[o];
#pragma unroll
    for(int c = 0; c < 64; ++c) acc = fmaf(w[o*64 + c], h[c], acc);
    atomicAdd(&sm_sum[o*33 + col], acc);
    atomicAdd(&sm_sq [o*33 + col], acc*acc);
  }
  __syncthreads();
  if(tid < 64){
    float s = 0.f;
#pragma unroll
    for(int c = 0; c < 32; ++c) s += sm_sum[tid*33 + c];
    atomicAdd(&gstats1[tid], s);
  } else if(tid < 128){
    int o = tid - 64; float s = 0.f;
#pragma unroll
    for(int c = 0; c < 32; ++c) s += sm_sq[o*33 + c];
    atomicAdd(&gstats1[64 + o], s);
  }
}

// ---------------------------------------------------------------------------
// 5) Layer 3: recompute L2 (BN0+ReLU -> GEMM), BN1+ReLU, L3 GEMM (64->128),
//    fused stats2 + max/min over the K=32 group (shuffle tree).
//    maxk/mink are fp32 in (bs, o) layout == final output layout.
// ---------------------------------------------------------------------------
__global__ __launch_bounds__(256) void layer3_kernel(const uint16_t* __restrict__ y1,
                                                     const float* __restrict__ gstats0,
                                                     const float* __restrict__ g0,
                                                     const float* __restrict__ bt0,
                                                     const float* __restrict__ w1,
                                                     const float* __restrict__ b1,
                                                     const float* __restrict__ gstats1,
                                                     const float* __restrict__ g1,
                                                     const float* __restrict__ bt1,
                                                     const float* __restrict__ w2,
                                                     const float* __restrict__ b2,
                                                     float* __restrict__ gstats2,
                                                     float* __restrict__ maxk,
                                                     float* __restrict__ mink){
  __shared__ float la0[64], lb0[64], la1[64], lb1[64];
  __shared__ float sm_sum[128*33];
  __shared__ float sm_sq [128*33];
  const int tid = threadIdx.x;
  for(int i = tid; i < 128*33; i += 256){ sm_sum[i] = 0.f; sm_sq[i] = 0.f; }
  if(tid < 64){
    float mean = gstats0[tid] * (1.0f / M_);
    float var  = gstats0[64 + tid] * (1.0f / M_) - mean * mean;
    float inv  = 1.0f / sqrtf(var + EPS_);
    float a = g0[tid] * inv;
    la0[tid] = a; lb0[tid] = bt0[tid] - mean * a;
  } else if(tid < 128){
    int o = tid - 64;
    float mean = gstats1[o] * (1.0f / M_);
    float var  = gstats1[64 + o] * (1.0f / M_) - mean * mean;
    float inv  = 1.0f / sqrtf(var + EPS_);
    float a = g1[o] * inv;
    la1[o] = a; lb1[o] = bt1[o] - mean * a;
  }
  __syncthreads();

  const int m = blockIdx.x * 256 + tid;
  const int bs = m >> 5;
  float h1[64];
#pragma unroll
  for(int c = 0; c < 64; ++c){
    float v = bf2f(y1[(size_t)c * M_ + m]);
    h1[c] = fmaxf(la0[c] * v + lb0[c], 0.0f);
  }
  float h2[64];
  for(int o = 0; o < 64; ++o){
    float acc = b1[o];
#pragma unroll
    for(int c = 0; c < 64; ++c) acc = fmaf(w1[o*64 + c], h1[c], acc);
    h2[o] = fmaxf(la1[o] * acc + lb1[o], 0.0f);
  }
  const int col = tid & 31;
  for(int o = 0; o < 128; ++o){
    float acc = b2[o];
#pragma unroll
    for(int c = 0; c < 64; ++c) acc = fmaf(w2[o*64 + c], h2[c], acc);
    atomicAdd(&sm_sum[o*33 + col], acc);
    atomicAdd(&sm_sq [o*33 + col], acc*acc);
    float mx = acc, mn = acc;
#pragma unroll
    for(int off = 1; off < 32; off <<= 1){       // stays within the 32-lane k-group
      mx = fmaxf(mx, __shfl_xor(mx, off, 64));
      mn = fminf(mn, __shfl_xor(mn, off, 64));
    }
    if((tid & 31) == 0){
      maxk[(size_t)bs * 128 + o] = mx;
      mink[(size_t)bs * 128 + o] = mn;
    }
  }
  __syncthreads();
  if(tid < 128){
    float s = 0.f;
#pragma unroll
    for(int c = 0; c < 32; ++c) s += sm_sum[tid*33 + c];
    atomicAdd(&gstats2[tid], s);
  } else {
    int o = tid - 128; float s = 0.f;
#pragma unroll
    for(int c = 0; c < 32; ++c) s += sm_sq[o*33 + c];
    atomicAdd(&gstats2[128 + o], s);
  }
}

// ---------------------------------------------------------------------------
// 6) Final: BN2+ReLU applied to max/min endpoints (max_k relu(a*v+b) =
//    max(relu(a*mx+b), relu(a*mn+b)) for either sign of a). Fully coalesced.
// ---------------------------------------------------------------------------
__global__ __launch_bounds__(256) void final_kernel(const float* __restrict__ maxk,
                                                    const float* __restrict__ mink,
                                                    const float* __restrict__ gstats2,
                                                    const float* __restrict__ g,
                                                    const float* __restrict__ bt,
                                                    float* __restrict__ out_np){
  const int gid = blockIdx.x * 256 + threadIdx.x;   // == bs*128 + o
  const int o = gid & 127;
  float mean = gstats2[o] * (1.0f / M_);
  float var  = gstats2[128 + o] * (1.0f / M_) - mean * mean;
  float inv  = 1.0f / sqrtf(var + EPS_);
  float a = g[o] * inv;
  float b = bt[o] - mean * a;
  float mx = maxk[gid], mn = mink[gid];
  out_np[gid] = fmaxf(fmaxf(a * mx + b, 0.0f), fmaxf(a * mn + b, 0.0f));
}

// ---------------------------------------------------------------------------
extern "C" void kernel_launch(void* const* d_in, const int* in_sizes, int n_in,
                              void* d_out, int out_size, void* d_ws, size_t ws_size,
                              hipStream_t stream){
  (void)in_sizes; (void)n_in; (void)out_size;
  const float* xyz = (const float*)d_in[0];
  const float* pts = (const float*)d_in[1];
  const float* w0 = (const float*)d_in[2];  const float* b0  = (const float*)d_in[3];
  const float* g0 = (const float*)d_in[4];  const float* bt0 = (const float*)d_in[5];
  const float* w1 = (const float*)d_in[6];  const float* b1  = (const float*)d_in[7];
  const float* g1 = (const float*)d_in[8];  const float* bt1 = (const float*)d_in[9];
  const float* w2 = (const float*)d_in[10]; const float* b2  = (const float*)d_in[11];
  const float* g2 = (const float*)d_in[12]; const float* bt2 = (const float*)d_in[13];

  float* out    = (float*)d_out;
  float* newxyz = out;                       // (B,S,3)
  float* newpts = out + (size_t)B_ * S_ * 3; // (B,S,128)

  // Workspace layout (total ~82.1 MB):
  const size_t off_gidx  = 0;
  const size_t off_stats = off_gidx  + (size_t)M_ * 4;
  const size_t off_maxk  = off_stats + 65536;
  const size_t off_mink  = off_maxk  + (size_t)NQ_ * 128 * 4;
  const size_t off_y1    = off_mink  + (size_t)NQ_ * 128 * 4;
  const size_t need      = off_y1    + (size_t)M_ * 64 * 2;
  if(ws_size < need) return;   // graceful failure instead of a device fault

  char* ws = (char*)d_ws;
  int*      gidx   = (int*)     (ws + off_gidx);
  float*    gstats = (float*)   (ws + off_stats);
  float*    maxk   = (float*)   (ws + off_maxk);
  float*    mink   = (float*)   (ws + off_mink);
  uint16_t* y1     = (uint16_t*)(ws + off_y1);

  zero_stats_kernel<<<2, 256, 0, stream>>>(gstats);
  fps_kernel  <<<B_, 1024, 0, stream>>>(xyz, newxyz);
  ballq_kernel<<<NQ_ / 4, 256, 0, stream>>>(xyz, newxyz, gidx);

  layer1_kernel      <<<M_ / 256, 256, 0, stream>>>(xyz, pts, newxyz, gidx, w0, b0, y1, gstats);
  layer2_stats_kernel<<<M_ / 256, 256, 0, stream>>>(y1, gstats, g0, bt0, w1, b1, gstats + 128);
  layer3_kernel      <<<M_ / 256, 256, 0, stream>>>(y1, gstats, g0, bt0, w1, b1,
                                                    gstats + 128, g1, bt1, w2, b2,
                                                    gstats + 256, maxk, mink);
  final_kernel<<<(NQ_ * 128) / 256, 256, 0, stream>>>(maxk, mink, gstats + 256, g2, bt2, newpts);
}

// Round 5
// 2489.051 us; speedup vs baseline: 1.6616x; 1.3239x over previous
//
#include <hip/hip_runtime.h>
#include <stdint.h>

#define B_ 16
#define N_ 4096
#define D_ 64
#define S_ 1024
#define K_ 32
#define M_ (B_*S_*K_)   /* 524288 */
#define NQ_ (B_*S_)     /* 16384 */
#define EPS_ 1e-5f

static __device__ __forceinline__ float bf2f(uint16_t u){
  union{uint32_t i; float f;} v; v.i = ((uint32_t)u) << 16; return v.f;
}
static __device__ __forceinline__ uint16_t f2bf(float f){
  union{uint32_t i; float f;} v; v.f = f;
  uint32_t u = v.i;
  uint32_t r = (u + 0x7FFFu + ((u >> 16) & 1u)) >> 16;   // RNE, finite inputs
  return (uint16_t)r;
}

// ---------------------------------------------------------------------------
// 0) Zero the global stats accumulators (ws is poisoned 0xAA before launch).
// ---------------------------------------------------------------------------
__global__ __launch_bounds__(256) void zero_stats_kernel(float* __restrict__ s){
  s[blockIdx.x * 256 + threadIdx.x] = 0.0f;   // grid 2 -> 512 floats
}

// ---------------------------------------------------------------------------
// 1) Farthest point sampling. One block/batch, 256 threads (4 waves = 1/SIMD,
//    so the VALU update runs unserialized), 16 pts/thread in registers.
//    Per iteration: local argmax over 16 pts -> u64 key (distbits<<32 | ~idx;
//    positive-float bits monotone, ~idx -> lowest index wins ties = jnp.argmax),
//    6-level u64 shuffle tree (only 4 waves on the LDS pipe now), ONE barrier,
//    all 4 waves redundantly reduce the 4 per-wave keys, winner coords from a
//    float4 LDS cache via a single broadcast ds_read_b128.
//    Distance math bit-identical to the round-3/4 verified kernel.
// ---------------------------------------------------------------------------
__global__ __launch_bounds__(256) void fps_kernel(const float* __restrict__ xyz,
                                                  float* __restrict__ out_newxyz){
  const int b = blockIdx.x;
  const int tid = threadIdx.x;
  const float* X = xyz + (size_t)b * N_ * 3;
  __shared__ float4 sxyz[N_];                       // 64 KB coord cache
  __shared__ unsigned long long slots[2][4];        // parity double-buffered
  float px[16], py[16], pz[16], dist[16];
#pragma unroll
  for(int t = 0; t < 16; ++t){
    int p = tid + t * 256;
    px[t] = X[p*3 + 0]; py[t] = X[p*3 + 1]; pz[t] = X[p*3 + 2];
    dist[t] = 1e10f;
    sxyz[p] = make_float4(px[t], py[t], pz[t], 0.0f);
  }
  __syncthreads();
  int far = 0;                                      // reference: idx[0] = 0
  for(int it = 0; it < S_; ++it){
    float4 c = sxyz[far];                           // broadcast b128 read
    if(tid == 0){
      float* o = out_newxyz + ((size_t)b * S_ + it) * 3;
      o[0] = c.x; o[1] = c.y; o[2] = c.z;
    }
    if(it == S_ - 1) break;
    float bestd = -1.0f; int bestp = 0;
#pragma unroll
    for(int t = 0; t < 16; ++t){
      float d;
      {
#pragma clang fp contract(off)
        float dx = px[t] - c.x, dy = py[t] - c.y, dz = pz[t] - c.z;
        d = dx*dx + dy*dy + dz*dz;   // match reference: plain mul/add, left-to-right
      }
      float nd = fminf(dist[t], d);
      dist[t] = nd;
      if(nd > bestd){ bestd = nd; bestp = tid + t*256; }  // ascending idx -> first max
    }
    unsigned long long key = ((unsigned long long)__float_as_uint(bestd) << 32)
                           | (unsigned long long)(uint32_t)(~bestp);
#pragma unroll
    for(int off = 1; off < 64; off <<= 1){
      unsigned long long ok = __shfl_xor(key, off, 64);
      if(ok > key) key = ok;
    }
    const int par = it & 1;
    if((tid & 63) == 0) slots[par][tid >> 6] = key;
    __syncthreads();
    unsigned long long bk = slots[par][0];
#pragma unroll
    for(int w = 1; w < 4; ++w){
      unsigned long long ok = slots[par][w];
      if(ok > bk) bk = ok;
    }
    far = (int)(~(uint32_t)bk);                     // uniform across block
  }
}

// ---------------------------------------------------------------------------
// 2) Ball query: one wave per query. First 32 indices (ascending) with
//    sq <= r^2, pad with first. FP64 sq: bit-identical to the numpy float64
//    reference (verified round 3).
// ---------------------------------------------------------------------------
__global__ __launch_bounds__(256) void ballq_kernel(const float* __restrict__ xyz,
                                                    const float* __restrict__ newxyz,
                                                    int* __restrict__ gidx){
  const int wslot = threadIdx.x >> 6;
  const int lane  = threadIdx.x & 63;
  const int q = blockIdx.x * 4 + wslot;        // [0, NQ_)
  const int b = q >> 10;
  const float* X = xyz + (size_t)b * N_ * 3;
  const double R2D = 0.2 * 0.2;                // == Python 0.2**2
  double nx, ny, nz, sa;
  {
    const float* NP = newxyz + (size_t)q * 3;
    nx = (double)NP[0]; ny = (double)NP[1]; nz = (double)NP[2];
    sa = nx*nx + ny*ny + nz*nz;
  }
  __shared__ int sidx[4][K_];
  int count = 0;
  for(int base = 0; base < N_; base += 64){
    int p = base + lane;
    double pxv = (double)X[p*3 + 0], pyv = (double)X[p*3 + 1], pzv = (double)X[p*3 + 2];
    double sb = pxv*pxv + pyv*pyv + pzv*pzv;
    double dt = nx*pxv + ny*pyv + nz*pzv;
    double sq = sa + sb - 2.0 * dt;            // ((sa+sb) - 2*dot) like reference
    bool inb = !(sq > R2D);
    unsigned long long mask = __ballot(inb);
    int pos = count + __popcll(mask & ((1ull << lane) - 1ull));
    if(inb && pos < K_) sidx[wslot][pos] = p;
    count += (int)__popcll(mask);
    if(count >= K_) break;                     // count is wave-uniform
  }
  __syncthreads();
  int nvalid = count < K_ ? count : K_;
  if(lane < K_){
    int first = sidx[wslot][0];               // count >= 1 always (self-point, sq == 0)
    int v = (lane < nvalid) ? sidx[wslot][lane] : first;
    gidx[(size_t)q * K_ + lane] = v;
  }
}

// ---------------------------------------------------------------------------
// 3) Layer 1: gather + concat + GEMM (67 -> 64) + bias. Writes y1 bf16 (64,M)
//    and accumulates per-channel sum/sumsq (fused, fp32) into gstats0.
// ---------------------------------------------------------------------------
__global__ __launch_bounds__(256) void layer1_kernel(const float* __restrict__ xyz,
                                                     const float* __restrict__ pts,
                                                     const float* __restrict__ newxyz,
                                                     const int* __restrict__ gidx,
                                                     const float* __restrict__ w,
                                                     const float* __restrict__ bias,
                                                     uint16_t* __restrict__ y,
                                                     float* __restrict__ gstats){
  __shared__ float sm_sum[64*33];
  __shared__ float sm_sq [64*33];
  const int tid = threadIdx.x;
  for(int i = tid; i < 64*33; i += 256){ sm_sum[i] = 0.f; sm_sq[i] = 0.f; }
  __syncthreads();

  const int m = blockIdx.x * 256 + tid;
  const int bs = m >> 5;
  const int b  = bs >> 10;
  const int j  = gidx[m];
  float x[67];
  {
    const float* nxp = newxyz + (size_t)bs * 3;
    const float* pp  = xyz + ((size_t)b * N_ + j) * 3;
    x[0] = pp[0] - nxp[0]; x[1] = pp[1] - nxp[1]; x[2] = pp[2] - nxp[2];
  }
  {
    const float4* pr = (const float4*)(pts + ((size_t)b * N_ + j) * D_);
#pragma unroll
    for(int c4 = 0; c4 < 16; ++c4){
      float4 v = pr[c4];
      x[3 + c4*4 + 0] = v.x; x[3 + c4*4 + 1] = v.y;
      x[3 + c4*4 + 2] = v.z; x[3 + c4*4 + 3] = v.w;
    }
  }
  const int col = tid & 31;
  for(int o = 0; o < 64; ++o){
    float acc = bias[o];
#pragma unroll
    for(int c = 0; c < 67; ++c) acc = fmaf(w[o*67 + c], x[c], acc);  // w uniform -> s_load
    y[(size_t)o * M_ + m] = f2bf(acc);
    atomicAdd(&sm_sum[o*33 + col], acc);        // ds_add_f32, 2 lanes/bank
    atomicAdd(&sm_sq [o*33 + col], acc*acc);
  }
  __syncthreads();
  if(tid < 64){
    float s = 0.f;
#pragma unroll
    for(int c = 0; c < 32; ++c) s += sm_sum[tid*33 + c];
    atomicAdd(&gstats[tid], s);
  } else if(tid < 128){
    int o = tid - 64; float s = 0.f;
#pragma unroll
    for(int c = 0; c < 32; ++c) s += sm_sq[o*33 + c];
    atomicAdd(&gstats[64 + o], s);
  }
}

// ---------------------------------------------------------------------------
// 4) Layer 2 (stats only): BN0+ReLU on y1, GEMM (64->64)+bias, accumulate
//    per-channel sum/sumsq into gstats1. No activation tensor is written;
//    layer 3 recomputes the identical values (deterministic same-order fma).
// ---------------------------------------------------------------------------
__global__ __launch_bounds__(256) void layer2_stats_kernel(const uint16_t* __restrict__ y1,
                                                           const float* __restrict__ gstats0,
                                                           const float* __restrict__ g,
                                                           const float* __restrict__ bt,
                                                           const float* __restrict__ w,
                                                           const float* __restrict__ bias,
                                                           float* __restrict__ gstats1){
  __shared__ float la[64], lb[64];
  __shared__ float sm_sum[64*33];
  __shared__ float sm_sq [64*33];
  const int tid = threadIdx.x;
  for(int i = tid; i < 64*33; i += 256){ sm_sum[i] = 0.f; sm_sq[i] = 0.f; }
  if(tid < 64){
    float mean = gstats0[tid] * (1.0f / M_);
    float var  = gstats0[64 + tid] * (1.0f / M_) - mean * mean;
    float inv  = 1.0f / sqrtf(var + EPS_);
    float a = g[tid] * inv;
    la[tid] = a; lb[tid] = bt[tid] - mean * a;
  }
  __syncthreads();

  const int m = blockIdx.x * 256 + tid;
  float h[64];
#pragma unroll
  for(int c = 0; c < 64; ++c){
    float v = bf2f(y1[(size_t)c * M_ + m]);
    h[c] = fmaxf(la[c] * v + lb[c], 0.0f);
  }
  const int col = tid & 31;
  for(int o = 0; o < 64; ++o){
    float acc = bias[o];
#pragma unroll
    for(int c = 0; c < 64; ++c) acc = fmaf(w[o*64 + c], h[c], acc);
    atomicAdd(&sm_sum[o*33 + col], acc);
    atomicAdd(&sm_sq [o*33 + col], acc*acc);
  }
  __syncthreads();
  if(tid < 64){
    float s = 0.f;
#pragma unroll
    for(int c = 0; c < 32; ++c) s += sm_sum[tid*33 + c];
    atomicAdd(&gstats1[tid], s);
  } else if(tid < 128){
    int o = tid - 64; float s = 0.f;
#pragma unroll
    for(int c = 0; c < 32; ++c) s += sm_sq[o*33 + c];
    atomicAdd(&gstats1[64 + o], s);
  }
}

// ---------------------------------------------------------------------------
// 5) Layer 3: recompute L2 (BN0+ReLU -> GEMM), BN1+ReLU, L3 GEMM (64->128),
//    fused stats2 + max/min over the K=32 group (shuffle tree).
//    maxk/mink are fp32 in (bs, o) layout == final output layout.
// ---------------------------------------------------------------------------
__global__ __launch_bounds__(256) void layer3_kernel(const uint16_t* __restrict__ y1,
                                                     const float* __restrict__ gstats0,
                                                     const float* __restrict__ g0,
                                                     const float* __restrict__ bt0,
                                                     const float* __restrict__ w1,
                                                     const float* __restrict__ b1,
                                                     const float* __restrict__ gstats1,
                                                     const float* __restrict__ g1,
                                                     const float* __restrict__ bt1,
                                                     const float* __restrict__ w2,
                                                     const float* __restrict__ b2,
                                                     float* __restrict__ gstats2,
                                                     float* __restrict__ maxk,
                                                     float* __restrict__ mink){
  __shared__ float la0[64], lb0[64], la1[64], lb1[64];
  __shared__ float sm_sum[128*33];
  __shared__ float sm_sq [128*33];
  const int tid = threadIdx.x;
  for(int i = tid; i < 128*33; i += 256){ sm_sum[i] = 0.f; sm_sq[i] = 0.f; }
  if(tid < 64){
    float mean = gstats0[tid] * (1.0f / M_);
    float var  = gstats0[64 + tid] * (1.0f / M_) - mean * mean;
    float inv  = 1.0f / sqrtf(var + EPS_);
    float a = g0[tid] * inv;
    la0[tid] = a; lb0[tid] = bt0[tid] - mean * a;
  } else if(tid < 128){
    int o = tid - 64;
    float mean = gstats1[o] * (1.0f / M_);
    float var  = gstats1[64 + o] * (1.0f / M_) - mean * mean;
    float inv  = 1.0f / sqrtf(var + EPS_);
    float a = g1[o] * inv;
    la1[o] = a; lb1[o] = bt1[o] - mean * a;
  }
  __syncthreads();

  const int m = blockIdx.x * 256 + tid;
  const int bs = m >> 5;
  float h1[64];
#pragma unroll
  for(int c = 0; c < 64; ++c){
    float v = bf2f(y1[(size_t)c * M_ + m]);
    h1[c] = fmaxf(la0[c] * v + lb0[c], 0.0f);
  }
  float h2[64];
  for(int o = 0; o < 64; ++o){
    float acc = b1[o];
#pragma unroll
    for(int c = 0; c < 64; ++c) acc = fmaf(w1[o*64 + c], h1[c], acc);
    h2[o] = fmaxf(la1[o] * acc + lb1[o], 0.0f);
  }
  const int col = tid & 31;
  for(int o = 0; o < 128; ++o){
    float acc = b2[o];
#pragma unroll
    for(int c = 0; c < 64; ++c) acc = fmaf(w2[o*64 + c], h2[c], acc);
    atomicAdd(&sm_sum[o*33 + col], acc);
    atomicAdd(&sm_sq [o*33 + col], acc*acc);
    float mx = acc, mn = acc;
#pragma unroll
    for(int off = 1; off < 32; off <<= 1){       // stays within the 32-lane k-group
      mx = fmaxf(mx, __shfl_xor(mx, off, 64));
      mn = fminf(mn, __shfl_xor(mn, off, 64));
    }
    if((tid & 31) == 0){
      maxk[(size_t)bs * 128 + o] = mx;
      mink[(size_t)bs * 128 + o] = mn;
    }
  }
  __syncthreads();
  if(tid < 128){
    float s = 0.f;
#pragma unroll
    for(int c = 0; c < 32; ++c) s += sm_sum[tid*33 + c];
    atomicAdd(&gstats2[tid], s);
  } else {
    int o = tid - 128; float s = 0.f;
#pragma unroll
    for(int c = 0; c < 32; ++c) s += sm_sq[o*33 + c];
    atomicAdd(&gstats2[128 + o], s);
  }
}

// ---------------------------------------------------------------------------
// 6) Final: BN2+ReLU applied to max/min endpoints (max_k relu(a*v+b) =
//    max(relu(a*mx+b), relu(a*mn+b)) for either sign of a). Fully coalesced.
// ---------------------------------------------------------------------------
__global__ __launch_bounds__(256) void final_kernel(const float* __restrict__ maxk,
                                                    const float* __restrict__ mink,
                                                    const float* __restrict__ gstats2,
                                                    const float* __restrict__ g,
                                                    const float* __restrict__ bt,
                                                    float* __restrict__ out_np){
  const int gid = blockIdx.x * 256 + threadIdx.x;   // == bs*128 + o
  const int o = gid & 127;
  float mean = gstats2[o] * (1.0f / M_);
  float var  = gstats2[128 + o] * (1.0f / M_) - mean * mean;
  float inv  = 1.0f / sqrtf(var + EPS_);
  float a = g[o] * inv;
  float b = bt[o] - mean * a;
  float mx = maxk[gid], mn = mink[gid];
  out_np[gid] = fmaxf(fmaxf(a * mx + b, 0.0f), fmaxf(a * mn + b, 0.0f));
}

// ---------------------------------------------------------------------------
extern "C" void kernel_launch(void* const* d_in, const int* in_sizes, int n_in,
                              void* d_out, int out_size, void* d_ws, size_t ws_size,
                              hipStream_t stream){
  (void)in_sizes; (void)n_in; (void)out_size;
  const float* xyz = (const float*)d_in[0];
  const float* pts = (const float*)d_in[1];
  const float* w0 = (const float*)d_in[2];  const float* b0  = (const float*)d_in[3];
  const float* g0 = (const float*)d_in[4];  const float* bt0 = (const float*)d_in[5];
  const float* w1 = (const float*)d_in[6];  const float* b1  = (const float*)d_in[7];
  const float* g1 = (const float*)d_in[8];  const float* bt1 = (const float*)d_in[9];
  const float* w2 = (const float*)d_in[10]; const float* b2  = (const float*)d_in[11];
  const float* g2 = (const float*)d_in[12]; const float* bt2 = (const float*)d_in[13];

  float* out    = (float*)d_out;
  float* newxyz = out;                       // (B,S,3)
  float* newpts = out + (size_t)B_ * S_ * 3; // (B,S,128)

  // Workspace layout (total ~82.1 MB):
  const size_t off_gidx  = 0;
  const size_t off_stats = off_gidx  + (size_t)M_ * 4;
  const size_t off_maxk  = off_stats + 65536;
  const size_t off_mink  = off_maxk  + (size_t)NQ_ * 128 * 4;
  const size_t off_y1    = off_mink  + (size_t)NQ_ * 128 * 4;
  const size_t need      = off_y1    + (size_t)M_ * 64 * 2;
  if(ws_size < need) return;   // graceful failure instead of a device fault

  char* ws = (char*)d_ws;
  int*      gidx   = (int*)     (ws + off_gidx);
  float*    gstats = (float*)   (ws + off_stats);
  float*    maxk   = (float*)   (ws + off_maxk);
  float*    mink   = (float*)   (ws + off_mink);
  uint16_t* y1     = (uint16_t*)(ws + off_y1);

  zero_stats_kernel<<<2, 256, 0, stream>>>(gstats);
  fps_kernel  <<<B_, 256, 0, stream>>>(xyz, newxyz);
  ballq_kernel<<<NQ_ / 4, 256, 0, stream>>>(xyz, newxyz, gidx);

  layer1_kernel      <<<M_ / 256, 256, 0, stream>>>(xyz, pts, newxyz, gidx, w0, b0, y1, gstats);
  layer2_stats_kernel<<<M_ / 256, 256, 0, stream>>>(y1, gstats, g0, bt0, w1, b1, gstats + 128);
  layer3_kernel      <<<M_ / 256, 256, 0, stream>>>(y1, gstats, g0, bt0, w1, b1,
                                                    gstats + 128, g1, bt1, w2, b2,
                                                    gstats + 256, maxk, mink);
  final_kernel<<<(NQ_ * 128) / 256, 256, 0, stream>>>(maxk, mink, gstats + 256, g2, bt2, newpts);
}

// Round 6
// 2426.222 us; speedup vs baseline: 1.7047x; 1.0259x over previous
//
#include <hip/hip_runtime.h>
#include <stdint.h>

#define B_ 16
#define N_ 4096
#define D_ 64
#define S_ 1024
#define K_ 32
#define M_ (B_*S_*K_)   /* 524288 */
#define NQ_ (B_*S_)     /* 16384 */
#define EPS_ 1e-5f

static __device__ __forceinline__ float bf2f(uint16_t u){
  union{uint32_t i; float f;} v; v.i = ((uint32_t)u) << 16; return v.f;
}
static __device__ __forceinline__ uint16_t f2bf(float f){
  union{uint32_t i; float f;} v; v.f = f;
  uint32_t u = v.i;
  uint32_t r = (u + 0x7FFFu + ((u >> 16) & 1u)) >> 16;   // RNE, finite inputs
  return (uint16_t)r;
}

// ---------------------------------------------------------------------------
// 0) Zero the global stats accumulators (ws is poisoned 0xAA before launch).
// ---------------------------------------------------------------------------
__global__ __launch_bounds__(256) void zero_stats_kernel(float* __restrict__ s){
  s[blockIdx.x * 256 + threadIdx.x] = 0.0f;   // grid 2 -> 512 floats
}

// ---------------------------------------------------------------------------
// 1) Farthest point sampling. One block/batch, 256 threads (4 waves = 1/SIMD),
//    16 pts/thread in registers. u64-key argmax (distbits<<32 | ~idx), 6-level
//    shuffle tree, ONE barrier, redundant 4-slot reduce, float4 LDS coord
//    cache. Distance math bit-identical to the verified round-3/4/5 kernel.
// ---------------------------------------------------------------------------
__global__ __launch_bounds__(256) void fps_kernel(const float* __restrict__ xyz,
                                                  float* __restrict__ out_newxyz){
  const int b = blockIdx.x;
  const int tid = threadIdx.x;
  const float* X = xyz + (size_t)b * N_ * 3;
  __shared__ float4 sxyz[N_];                       // 64 KB coord cache
  __shared__ unsigned long long slots[2][4];        // parity double-buffered
  float px[16], py[16], pz[16], dist[16];
#pragma unroll
  for(int t = 0; t < 16; ++t){
    int p = tid + t * 256;
    px[t] = X[p*3 + 0]; py[t] = X[p*3 + 1]; pz[t] = X[p*3 + 2];
    dist[t] = 1e10f;
    sxyz[p] = make_float4(px[t], py[t], pz[t], 0.0f);
  }
  __syncthreads();
  int far = 0;                                      // reference: idx[0] = 0
  for(int it = 0; it < S_; ++it){
    float4 c = sxyz[far];                           // broadcast b128 read
    if(tid == 0){
      float* o = out_newxyz + ((size_t)b * S_ + it) * 3;
      o[0] = c.x; o[1] = c.y; o[2] = c.z;
    }
    if(it == S_ - 1) break;
    float bestd = -1.0f; int bestp = 0;
#pragma unroll
    for(int t = 0; t < 16; ++t){
      float d;
      {
#pragma clang fp contract(off)
        float dx = px[t] - c.x, dy = py[t] - c.y, dz = pz[t] - c.z;
        d = dx*dx + dy*dy + dz*dz;   // match reference: plain mul/add, left-to-right
      }
      float nd = fminf(dist[t], d);
      dist[t] = nd;
      if(nd > bestd){ bestd = nd; bestp = tid + t*256; }  // ascending idx -> first max
    }
    unsigned long long key = ((unsigned long long)__float_as_uint(bestd) << 32)
                           | (unsigned long long)(uint32_t)(~bestp);
#pragma unroll
    for(int off = 1; off < 64; off <<= 1){
      unsigned long long ok = __shfl_xor(key, off, 64);
      if(ok > key) key = ok;
    }
    const int par = it & 1;
    if((tid & 63) == 0) slots[par][tid >> 6] = key;
    __syncthreads();
    unsigned long long bk = slots[par][0];
#pragma unroll
    for(int w = 1; w < 4; ++w){
      unsigned long long ok = slots[par][w];
      if(ok > bk) bk = ok;
    }
    far = (int)(~(uint32_t)bk);                     // uniform across block
  }
}

// ---------------------------------------------------------------------------
// 2) Ball query: one wave per query. First 32 indices (ascending) with
//    sq <= r^2, pad with first. FP64 sq: bit-identical to the numpy float64
//    reference (verified round 3).
// ---------------------------------------------------------------------------
__global__ __launch_bounds__(256) void ballq_kernel(const float* __restrict__ xyz,
                                                    const float* __restrict__ newxyz,
                                                    int* __restrict__ gidx){
  const int wslot = threadIdx.x >> 6;
  const int lane  = threadIdx.x & 63;
  const int q = blockIdx.x * 4 + wslot;        // [0, NQ_)
  const int b = q >> 10;
  const float* X = xyz + (size_t)b * N_ * 3;
  const double R2D = 0.2 * 0.2;                // == Python 0.2**2
  double nx, ny, nz, sa;
  {
    const float* NP = newxyz + (size_t)q * 3;
    nx = (double)NP[0]; ny = (double)NP[1]; nz = (double)NP[2];
    sa = nx*nx + ny*ny + nz*nz;
  }
  __shared__ int sidx[4][K_];
  int count = 0;
  for(int base = 0; base < N_; base += 64){
    int p = base + lane;
    double pxv = (double)X[p*3 + 0], pyv = (double)X[p*3 + 1], pzv = (double)X[p*3 + 2];
    double sb = pxv*pxv + pyv*pyv + pzv*pzv;
    double dt = nx*pxv + ny*pyv + nz*pzv;
    double sq = sa + sb - 2.0 * dt;            // ((sa+sb) - 2*dot) like reference
    bool inb = !(sq > R2D);
    unsigned long long mask = __ballot(inb);
    int pos = count + __popcll(mask & ((1ull << lane) - 1ull));
    if(inb && pos < K_) sidx[wslot][pos] = p;
    count += (int)__popcll(mask);
    if(count >= K_) break;                     // count is wave-uniform
  }
  __syncthreads();
  int nvalid = count < K_ ? count : K_;
  if(lane < K_){
    int first = sidx[wslot][0];               // count >= 1 always (self-point, sq == 0)
    int v = (lane < nvalid) ? sidx[wslot][lane] : first;
    gidx[(size_t)q * K_ + lane] = v;
  }
}

// ---------------------------------------------------------------------------
// 3) Layer 1: gather + concat + GEMM (67 -> 64) + bias. Writes y1 bf16 (64,M)
//    and accumulates per-channel sum/sumsq (fused, fp32) into gstats0.
//    __launch_bounds__(256,4): 128-VGPR cap so x[67] stays in registers
//    (the unconstrained build spilled; see round-5 WRITE_SIZE evidence).
// ---------------------------------------------------------------------------
__global__ __launch_bounds__(256, 4) void layer1_kernel(const float* __restrict__ xyz,
                                                     const float* __restrict__ pts,
                                                     const float* __restrict__ newxyz,
                                                     const int* __restrict__ gidx,
                                                     const float* __restrict__ w,
                                                     const float* __restrict__ bias,
                                                     uint16_t* __restrict__ y,
                                                     float* __restrict__ gstats){
  __shared__ float sm_sum[64*33];
  __shared__ float sm_sq [64*33];
  const int tid = threadIdx.x;
  for(int i = tid; i < 64*33; i += 256){ sm_sum[i] = 0.f; sm_sq[i] = 0.f; }
  __syncthreads();

  const int m = blockIdx.x * 256 + tid;
  const int bs = m >> 5;
  const int b  = bs >> 10;
  const int j  = gidx[m];
  float x[67];
  {
    const float* nxp = newxyz + (size_t)bs * 3;
    const float* pp  = xyz + ((size_t)b * N_ + j) * 3;
    x[0] = pp[0] - nxp[0]; x[1] = pp[1] - nxp[1]; x[2] = pp[2] - nxp[2];
  }
  {
    const float4* pr = (const float4*)(pts + ((size_t)b * N_ + j) * D_);
#pragma unroll
    for(int c4 = 0; c4 < 16; ++c4){
      float4 v = pr[c4];
      x[3 + c4*4 + 0] = v.x; x[3 + c4*4 + 1] = v.y;
      x[3 + c4*4 + 2] = v.z; x[3 + c4*4 + 3] = v.w;
    }
  }
  const int col = tid & 31;
  for(int o = 0; o < 64; ++o){
    float acc = bias[o];
#pragma unroll
    for(int c = 0; c < 67; ++c) acc = fmaf(w[o*67 + c], x[c], acc);  // w uniform -> s_load
    y[(size_t)o * M_ + m] = f2bf(acc);
    atomicAdd(&sm_sum[o*33 + col], acc);        // ds_add_f32, 2 lanes/bank
    atomicAdd(&sm_sq [o*33 + col], acc*acc);
  }
  __syncthreads();
  if(tid < 64){
    float s = 0.f;
#pragma unroll
    for(int c = 0; c < 32; ++c) s += sm_sum[tid*33 + c];
    atomicAdd(&gstats[tid], s);
  } else if(tid < 128){
    int o = tid - 64; float s = 0.f;
#pragma unroll
    for(int c = 0; c < 32; ++c) s += sm_sq[o*33 + c];
    atomicAdd(&gstats[64 + o], s);
  }
}

// ---------------------------------------------------------------------------
// 4) Layer 2 (stats only): BN0+ReLU on y1, GEMM (64->64)+bias, accumulate
//    per-channel sum/sumsq into gstats1. Layer 3 recomputes the identical
//    values (same fma order). __launch_bounds__(256,4): h[64] stays in regs.
// ---------------------------------------------------------------------------
__global__ __launch_bounds__(256, 4) void layer2_stats_kernel(const uint16_t* __restrict__ y1,
                                                           const float* __restrict__ gstats0,
                                                           const float* __restrict__ g,
                                                           const float* __restrict__ bt,
                                                           const float* __restrict__ w,
                                                           const float* __restrict__ bias,
                                                           float* __restrict__ gstats1){
  __shared__ float la[64], lb[64];
  __shared__ float sm_sum[64*33];
  __shared__ float sm_sq [64*33];
  const int tid = threadIdx.x;
  for(int i = tid; i < 64*33; i += 256){ sm_sum[i] = 0.f; sm_sq[i] = 0.f; }
  if(tid < 64){
    float mean = gstats0[tid] * (1.0f / M_);
    float var  = gstats0[64 + tid] * (1.0f / M_) - mean * mean;
    float inv  = 1.0f / sqrtf(var + EPS_);
    float a = g[tid] * inv;
    la[tid] = a; lb[tid] = bt[tid] - mean * a;
  }
  __syncthreads();

  const int m = blockIdx.x * 256 + tid;
  float h[64];
#pragma unroll
  for(int c = 0; c < 64; ++c){
    float v = bf2f(y1[(size_t)c * M_ + m]);
    h[c] = fmaxf(la[c] * v + lb[c], 0.0f);
  }
  const int col = tid & 31;
  for(int o = 0; o < 64; ++o){
    float acc = bias[o];
#pragma unroll
    for(int c = 0; c < 64; ++c) acc = fmaf(w[o*64 + c], h[c], acc);
    atomicAdd(&sm_sum[o*33 + col], acc);
    atomicAdd(&sm_sq [o*33 + col], acc*acc);
  }
  __syncthreads();
  if(tid < 64){
    float s = 0.f;
#pragma unroll
    for(int c = 0; c < 32; ++c) s += sm_sum[tid*33 + c];
    atomicAdd(&gstats1[tid], s);
  } else if(tid < 128){
    int o = tid - 64; float s = 0.f;
#pragma unroll
    for(int c = 0; c < 32; ++c) s += sm_sq[o*33 + c];
    atomicAdd(&gstats1[64 + o], s);
  }
}

// ---------------------------------------------------------------------------
// 5) Layer 3, restructured to kill the round-5 spills (VGPR=72 + 135 MB of
//    scratch traffic). Phase A: L2 recompute c-OUTER -- only acc2[64] live;
//    each h1_c is produced and consumed immediately. Accumulation order per
//    output o is unchanged (c ascending, init b1[o]) => bit-identical to the
//    verified kernel. Then BN1+ReLU in place. Phase B: L3 GEMM o-outer with
//    h2[64] live (contiguous w2 scalar loads), fused stats2 + max/min over
//    the 32-lane k-group. Peak live ~80 regs; (256,4) caps at 128, no spill.
// ---------------------------------------------------------------------------
__global__ __launch_bounds__(256, 4) void layer3_kernel(const uint16_t* __restrict__ y1,
                                                     const float* __restrict__ gstats0,
                                                     const float* __restrict__ g0,
                                                     const float* __restrict__ bt0,
                                                     const float* __restrict__ w1,
                                                     const float* __restrict__ b1,
                                                     const float* __restrict__ gstats1,
                                                     const float* __restrict__ g1,
                                                     const float* __restrict__ bt1,
                                                     const float* __restrict__ w2,
                                                     const float* __restrict__ b2,
                                                     float* __restrict__ gstats2,
                                                     float* __restrict__ maxk,
                                                     float* __restrict__ mink){
  __shared__ float la0[64], lb0[64], la1[64], lb1[64];
  __shared__ float sm_sum[128*33];
  __shared__ float sm_sq [128*33];
  const int tid = threadIdx.x;
  for(int i = tid; i < 128*33; i += 256){ sm_sum[i] = 0.f; sm_sq[i] = 0.f; }
  if(tid < 64){
    float mean = gstats0[tid] * (1.0f / M_);
    float var  = gstats0[64 + tid] * (1.0f / M_) - mean * mean;
    float inv  = 1.0f / sqrtf(var + EPS_);
    float a = g0[tid] * inv;
    la0[tid] = a; lb0[tid] = bt0[tid] - mean * a;
  } else if(tid < 128){
    int o = tid - 64;
    float mean = gstats1[o] * (1.0f / M_);
    float var  = gstats1[64 + o] * (1.0f / M_) - mean * mean;
    float inv  = 1.0f / sqrtf(var + EPS_);
    float a = g1[o] * inv;
    la1[o] = a; lb1[o] = bt1[o] - mean * a;
  }
  __syncthreads();

  const int m = blockIdx.x * 256 + tid;
  const int bs = m >> 5;

  // Phase A: L2 recompute, c-outer. acc2[o] = b1[o] + sum_c w1[o][c]*h1_c,
  // fma order per o identical to the o-outer/c-inner original.
  float acc2[64];
#pragma unroll
  for(int o = 0; o < 64; ++o) acc2[o] = b1[o];
  for(int c = 0; c < 64; ++c){
    float v = bf2f(y1[(size_t)c * M_ + m]);
    float h1c = fmaxf(la0[c] * v + lb0[c], 0.0f);
#pragma unroll
    for(int o = 0; o < 64; ++o) acc2[o] = fmaf(w1[o*64 + c], h1c, acc2[o]);
  }
#pragma unroll
  for(int o = 0; o < 64; ++o) acc2[o] = fmaxf(la1[o] * acc2[o] + lb1[o], 0.0f); // h2 in place

  // Phase B: L3 GEMM, o-outer, contiguous w2 reads; fused stats + k-max/min.
  const int col = tid & 31;
  for(int o = 0; o < 128; ++o){
    float acc = b2[o];
#pragma unroll
    for(int c = 0; c < 64; ++c) acc = fmaf(w2[o*64 + c], acc2[c], acc);
    atomicAdd(&sm_sum[o*33 + col], acc);
    atomicAdd(&sm_sq [o*33 + col], acc*acc);
    float mx = acc, mn = acc;
#pragma unroll
    for(int off = 1; off < 32; off <<= 1){       // stays within the 32-lane k-group
      mx = fmaxf(mx, __shfl_xor(mx, off, 64));
      mn = fminf(mn, __shfl_xor(mn, off, 64));
    }
    if((tid & 31) == 0){
      maxk[(size_t)bs * 128 + o] = mx;
      mink[(size_t)bs * 128 + o] = mn;
    }
  }
  __syncthreads();
  if(tid < 128){
    float s = 0.f;
#pragma unroll
    for(int c = 0; c < 32; ++c) s += sm_sum[tid*33 + c];
    atomicAdd(&gstats2[tid], s);
  } else {
    int o = tid - 128; float s = 0.f;
#pragma unroll
    for(int c = 0; c < 32; ++c) s += sm_sq[o*33 + c];
    atomicAdd(&gstats2[128 + o], s);
  }
}

// ---------------------------------------------------------------------------
// 6) Final: BN2+ReLU applied to max/min endpoints (max_k relu(a*v+b) =
//    max(relu(a*mx+b), relu(a*mn+b)) for either sign of a). Fully coalesced.
// ---------------------------------------------------------------------------
__global__ __launch_bounds__(256) void final_kernel(const float* __restrict__ maxk,
                                                    const float* __restrict__ mink,
                                                    const float* __restrict__ gstats2,
                                                    const float* __restrict__ g,
                                                    const float* __restrict__ bt,
                                                    float* __restrict__ out_np){
  const int gid = blockIdx.x * 256 + threadIdx.x;   // == bs*128 + o
  const int o = gid & 127;
  float mean = gstats2[o] * (1.0f / M_);
  float var  = gstats2[128 + o] * (1.0f / M_) - mean * mean;
  float inv  = 1.0f / sqrtf(var + EPS_);
  float a = g[o] * inv;
  float b = bt[o] - mean * a;
  float mx = maxk[gid], mn = mink[gid];
  out_np[gid] = fmaxf(fmaxf(a * mx + b, 0.0f), fmaxf(a * mn + b, 0.0f));
}

// ---------------------------------------------------------------------------
extern "C" void kernel_launch(void* const* d_in, const int* in_sizes, int n_in,
                              void* d_out, int out_size, void* d_ws, size_t ws_size,
                              hipStream_t stream){
  (void)in_sizes; (void)n_in; (void)out_size;
  const float* xyz = (const float*)d_in[0];
  const float* pts = (const float*)d_in[1];
  const float* w0 = (const float*)d_in[2];  const float* b0  = (const float*)d_in[3];
  const float* g0 = (const float*)d_in[4];  const float* bt0 = (const float*)d_in[5];
  const float* w1 = (const float*)d_in[6];  const float* b1  = (const float*)d_in[7];
  const float* g1 = (const float*)d_in[8];  const float* bt1 = (const float*)d_in[9];
  const float* w2 = (const float*)d_in[10]; const float* b2  = (const float*)d_in[11];
  const float* g2 = (const float*)d_in[12]; const float* bt2 = (const float*)d_in[13];

  float* out    = (float*)d_out;
  float* newxyz = out;                       // (B,S,3)
  float* newpts = out + (size_t)B_ * S_ * 3; // (B,S,128)

  // Workspace layout (total ~82.1 MB):
  const size_t off_gidx  = 0;
  const size_t off_stats = off_gidx  + (size_t)M_ * 4;
  const size_t off_maxk  = off_stats + 65536;
  const size_t off_mink  = off_maxk  + (size_t)NQ_ * 128 * 4;
  const size_t off_y1    = off_mink  + (size_t)NQ_ * 128 * 4;
  const size_t need      = off_y1    + (size_t)M_ * 64 * 2;
  if(ws_size < need) return;   // graceful failure instead of a device fault

  char* ws = (char*)d_ws;
  int*      gidx   = (int*)     (ws + off_gidx);
  float*    gstats = (float*)   (ws + off_stats);
  float*    maxk   = (float*)   (ws + off_maxk);
  float*    mink   = (float*)   (ws + off_mink);
  uint16_t* y1     = (uint16_t*)(ws + off_y1);

  zero_stats_kernel<<<2, 256, 0, stream>>>(gstats);
  fps_kernel  <<<B_, 256, 0, stream>>>(xyz, newxyz);
  ballq_kernel<<<NQ_ / 4, 256, 0, stream>>>(xyz, newxyz, gidx);

  layer1_kernel      <<<M_ / 256, 256, 0, stream>>>(xyz, pts, newxyz, gidx, w0, b0, y1, gstats);
  layer2_stats_kernel<<<M_ / 256, 256, 0, stream>>>(y1, gstats, g0, bt0, w1, b1, gstats + 128);
  layer3_kernel      <<<M_ / 256, 256, 0, stream>>>(y1, gstats, g0, bt0, w1, b1,
                                                    gstats + 128, g1, bt1, w2, b2,
                                                    gstats + 256, maxk, mink);
  final_kernel<<<(NQ_ * 128) / 256, 256, 0, stream>>>(maxk, mink, gstats + 256, g2, bt2, newpts);
}

// Round 7
// 2423.067 us; speedup vs baseline: 1.7069x; 1.0013x over previous
//
#include <hip/hip_runtime.h>
#include <stdint.h>

#define B_ 16
#define N_ 4096
#define D_ 64
#define S_ 1024
#define K_ 32
#define M_ (B_*S_*K_)   /* 524288 */
#define NQ_ (B_*S_)     /* 16384 */
#define EPS_ 1e-5f

static __device__ __forceinline__ float bf2f(uint16_t u){
  union{uint32_t i; float f;} v; v.i = ((uint32_t)u) << 16; return v.f;
}
static __device__ __forceinline__ uint16_t f2bf(float f){
  union{uint32_t i; float f;} v; v.f = f;
  uint32_t u = v.i;
  uint32_t r = (u + 0x7FFFu + ((u >> 16) & 1u)) >> 16;   // RNE, finite inputs
  return (uint16_t)r;
}

// ---------------------------------------------------------------------------
// 0) Zero the global stats accumulators (ws is poisoned 0xAA before launch).
// ---------------------------------------------------------------------------
__global__ __launch_bounds__(256) void zero_stats_kernel(float* __restrict__ s){
  s[blockIdx.x * 256 + threadIdx.x] = 0.0f;   // grid 2 -> 512 floats
}

// ---------------------------------------------------------------------------
// 1) Farthest point sampling. One block/batch, 256 threads (4 waves = 1/SIMD),
//    16 pts/thread in registers. u64-key argmax (distbits<<32 | ~idx), 6-level
//    shuffle tree, ONE barrier, redundant 4-slot reduce, float4 LDS coord
//    cache. Distance math bit-identical to the verified round-3/4/5 kernel.
// ---------------------------------------------------------------------------
__global__ __launch_bounds__(256) void fps_kernel(const float* __restrict__ xyz,
                                                  float* __restrict__ out_newxyz){
  const int b = blockIdx.x;
  const int tid = threadIdx.x;
  const float* X = xyz + (size_t)b * N_ * 3;
  __shared__ float4 sxyz[N_];                       // 64 KB coord cache
  __shared__ unsigned long long slots[2][4];        // parity double-buffered
  float px[16], py[16], pz[16], dist[16];
#pragma unroll
  for(int t = 0; t < 16; ++t){
    int p = tid + t * 256;
    px[t] = X[p*3 + 0]; py[t] = X[p*3 + 1]; pz[t] = X[p*3 + 2];
    dist[t] = 1e10f;
    sxyz[p] = make_float4(px[t], py[t], pz[t], 0.0f);
  }
  __syncthreads();
  int far = 0;                                      // reference: idx[0] = 0
  for(int it = 0; it < S_; ++it){
    float4 c = sxyz[far];                           // broadcast b128 read
    if(tid == 0){
      float* o = out_newxyz + ((size_t)b * S_ + it) * 3;
      o[0] = c.x; o[1] = c.y; o[2] = c.z;
    }
    if(it == S_ - 1) break;
    float bestd = -1.0f; int bestp = 0;
#pragma unroll
    for(int t = 0; t < 16; ++t){
      float d;
      {
#pragma clang fp contract(off)
        float dx = px[t] - c.x, dy = py[t] - c.y, dz = pz[t] - c.z;
        d = dx*dx + dy*dy + dz*dz;   // match reference: plain mul/add, left-to-right
      }
      float nd = fminf(dist[t], d);
      dist[t] = nd;
      if(nd > bestd){ bestd = nd; bestp = tid + t*256; }  // ascending idx -> first max
    }
    unsigned long long key = ((unsigned long long)__float_as_uint(bestd) << 32)
                           | (unsigned long long)(uint32_t)(~bestp);
#pragma unroll
    for(int off = 1; off < 64; off <<= 1){
      unsigned long long ok = __shfl_xor(key, off, 64);
      if(ok > key) key = ok;
    }
    const int par = it & 1;
    if((tid & 63) == 0) slots[par][tid >> 6] = key;
    __syncthreads();
    unsigned long long bk = slots[par][0];
#pragma unroll
    for(int w = 1; w < 4; ++w){
      unsigned long long ok = slots[par][w];
      if(ok > bk) bk = ok;
    }
    far = (int)(~(uint32_t)bk);                     // uniform across block
  }
}

// ---------------------------------------------------------------------------
// 2) Ball query: one wave per query. First 32 indices (ascending) with
//    sq <= r^2, pad with first. FP64 sq: bit-identical to the numpy float64
//    reference (verified round 3).
// ---------------------------------------------------------------------------
__global__ __launch_bounds__(256) void ballq_kernel(const float* __restrict__ xyz,
                                                    const float* __restrict__ newxyz,
                                                    int* __restrict__ gidx){
  const int wslot = threadIdx.x >> 6;
  const int lane  = threadIdx.x & 63;
  const int q = blockIdx.x * 4 + wslot;        // [0, NQ_)
  const int b = q >> 10;
  const float* X = xyz + (size_t)b * N_ * 3;
  const double R2D = 0.2 * 0.2;                // == Python 0.2**2
  double nx, ny, nz, sa;
  {
    const float* NP = newxyz + (size_t)q * 3;
    nx = (double)NP[0]; ny = (double)NP[1]; nz = (double)NP[2];
    sa = nx*nx + ny*ny + nz*nz;
  }
  __shared__ int sidx[4][K_];
  int count = 0;
  for(int base = 0; base < N_; base += 64){
    int p = base + lane;
    double pxv = (double)X[p*3 + 0], pyv = (double)X[p*3 + 1], pzv = (double)X[p*3 + 2];
    double sb = pxv*pxv + pyv*pyv + pzv*pzv;
    double dt = nx*pxv + ny*pyv + nz*pzv;
    double sq = sa + sb - 2.0 * dt;            // ((sa+sb) - 2*dot) like reference
    bool inb = !(sq > R2D);
    unsigned long long mask = __ballot(inb);
    int pos = count + __popcll(mask & ((1ull << lane) - 1ull));
    if(inb && pos < K_) sidx[wslot][pos] = p;
    count += (int)__popcll(mask);
    if(count >= K_) break;                     // count is wave-uniform
  }
  __syncthreads();
  int nvalid = count < K_ ? count : K_;
  if(lane < K_){
    int first = sidx[wslot][0];               // count >= 1 always (self-point, sq == 0)
    int v = (lane < nvalid) ? sidx[wslot][lane] : first;
    gidx[(size_t)q * K_ + lane] = v;
  }
}

// ---------------------------------------------------------------------------
// 3) Layer 1: gather + concat + GEMM (67 -> 64) + bias. Writes y1 bf16 (64,M)
//    and accumulates per-channel sum/sumsq (fused, fp32) into gstats0.
//    amdgpu_waves_per_eu(4,4): pins the allocator target at exactly 4
//    waves/EU = 128 VGPRs. Round-6 evidence: min-only bound left the
//    allocator chasing 8 waves/EU (VGPR=44!) and it rematerialized/spilled
//    x[]/h[] through scratch+L2 -- the 41 ms layer2 profile pathology.
// ---------------------------------------------------------------------------
__global__ __launch_bounds__(256)
__attribute__((amdgpu_waves_per_eu(4, 4)))
void layer1_kernel(const float* __restrict__ xyz,
                   const float* __restrict__ pts,
                   const float* __restrict__ newxyz,
                   const int* __restrict__ gidx,
                   const float* __restrict__ w,
                   const float* __restrict__ bias,
                   uint16_t* __restrict__ y,
                   float* __restrict__ gstats){
  __shared__ float sm_sum[64*33];
  __shared__ float sm_sq [64*33];
  const int tid = threadIdx.x;
  for(int i = tid; i < 64*33; i += 256){ sm_sum[i] = 0.f; sm_sq[i] = 0.f; }
  __syncthreads();

  const int m = blockIdx.x * 256 + tid;
  const int bs = m >> 5;
  const int b  = bs >> 10;
  const int j  = gidx[m];
  float x[67];
  {
    const float* nxp = newxyz + (size_t)bs * 3;
    const float* pp  = xyz + ((size_t)b * N_ + j) * 3;
    x[0] = pp[0] - nxp[0]; x[1] = pp[1] - nxp[1]; x[2] = pp[2] - nxp[2];
  }
  {
    const float4* pr = (const float4*)(pts + ((size_t)b * N_ + j) * D_);
#pragma unroll
    for(int c4 = 0; c4 < 16; ++c4){
      float4 v = pr[c4];
      x[3 + c4*4 + 0] = v.x; x[3 + c4*4 + 1] = v.y;
      x[3 + c4*4 + 2] = v.z; x[3 + c4*4 + 3] = v.w;
    }
  }
  const int col = tid & 31;
  for(int o = 0; o < 64; ++o){
    float acc = bias[o];
#pragma unroll
    for(int c = 0; c < 67; ++c) acc = fmaf(w[o*67 + c], x[c], acc);  // w uniform -> s_load
    y[(size_t)o * M_ + m] = f2bf(acc);
    atomicAdd(&sm_sum[o*33 + col], acc);        // ds_add_f32, 2 lanes/bank
    atomicAdd(&sm_sq [o*33 + col], acc*acc);
  }
  __syncthreads();
  if(tid < 64){
    float s = 0.f;
#pragma unroll
    for(int c = 0; c < 32; ++c) s += sm_sum[tid*33 + c];
    atomicAdd(&gstats[tid], s);
  } else if(tid < 128){
    int o = tid - 64; float s = 0.f;
#pragma unroll
    for(int c = 0; c < 32; ++c) s += sm_sq[o*33 + c];
    atomicAdd(&gstats[64 + o], s);
  }
}

// ---------------------------------------------------------------------------
// 4) Layer 2 (stats only): BN0+ReLU on y1, GEMM (64->64)+bias, accumulate
//    per-channel sum/sumsq into gstats1. Layer 3 recomputes the identical
//    values (same fma order). waves_per_eu(4,4): h[64] must stay in regs.
// ---------------------------------------------------------------------------
__global__ __launch_bounds__(256)
__attribute__((amdgpu_waves_per_eu(4, 4)))
void layer2_stats_kernel(const uint16_t* __restrict__ y1,
                         const float* __restrict__ gstats0,
                         const float* __restrict__ g,
                         const float* __restrict__ bt,
                         const float* __restrict__ w,
                         const float* __restrict__ bias,
                         float* __restrict__ gstats1){
  __shared__ float la[64], lb[64];
  __shared__ float sm_sum[64*33];
  __shared__ float sm_sq [64*33];
  const int tid = threadIdx.x;
  for(int i = tid; i < 64*33; i += 256){ sm_sum[i] = 0.f; sm_sq[i] = 0.f; }
  if(tid < 64){
    float mean = gstats0[tid] * (1.0f / M_);
    float var  = gstats0[64 + tid] * (1.0f / M_) - mean * mean;
    float inv  = 1.0f / sqrtf(var + EPS_);
    float a = g[tid] * inv;
    la[tid] = a; lb[tid] = bt[tid] - mean * a;
  }
  __syncthreads();

  const int m = blockIdx.x * 256 + tid;
  float h[64];
#pragma unroll
  for(int c = 0; c < 64; ++c){
    float v = bf2f(y1[(size_t)c * M_ + m]);
    h[c] = fmaxf(la[c] * v + lb[c], 0.0f);
  }
  const int col = tid & 31;
  for(int o = 0; o < 64; ++o){
    float acc = bias[o];
#pragma unroll
    for(int c = 0; c < 64; ++c) acc = fmaf(w[o*64 + c], h[c], acc);
    atomicAdd(&sm_sum[o*33 + col], acc);
    atomicAdd(&sm_sq [o*33 + col], acc*acc);
  }
  __syncthreads();
  if(tid < 64){
    float s = 0.f;
#pragma unroll
    for(int c = 0; c < 32; ++c) s += sm_sum[tid*33 + c];
    atomicAdd(&gstats1[tid], s);
  } else if(tid < 128){
    int o = tid - 64; float s = 0.f;
#pragma unroll
    for(int c = 0; c < 32; ++c) s += sm_sq[o*33 + c];
    atomicAdd(&gstats1[64 + o], s);
  }
}

// ---------------------------------------------------------------------------
// 5) Layer 3. Phase A: L2 recompute c-OUTER (only acc2[64] live; identical
//    per-o fma order -> bit-identical), BN1+ReLU in place. Phase B: L3 GEMM
//    o-outer, fused stats2 + max/min over the 32-lane k-group.
//    waves_per_eu(4,4): acc2[64] pinned in registers.
// ---------------------------------------------------------------------------
__global__ __launch_bounds__(256)
__attribute__((amdgpu_waves_per_eu(4, 4)))
void layer3_kernel(const uint16_t* __restrict__ y1,
                   const float* __restrict__ gstats0,
                   const float* __restrict__ g0,
                   const float* __restrict__ bt0,
                   const float* __restrict__ w1,
                   const float* __restrict__ b1,
                   const float* __restrict__ gstats1,
                   const float* __restrict__ g1,
                   const float* __restrict__ bt1,
                   const float* __restrict__ w2,
                   const float* __restrict__ b2,
                   float* __restrict__ gstats2,
                   float* __restrict__ maxk,
                   float* __restrict__ mink){
  __shared__ float la0[64], lb0[64], la1[64], lb1[64];
  __shared__ float sm_sum[128*33];
  __shared__ float sm_sq [128*33];
  const int tid = threadIdx.x;
  for(int i = tid; i < 128*33; i += 256){ sm_sum[i] = 0.f; sm_sq[i] = 0.f; }
  if(tid < 64){
    float mean = gstats0[tid] * (1.0f / M_);
    float var  = gstats0[64 + tid] * (1.0f / M_) - mean * mean;
    float inv  = 1.0f / sqrtf(var + EPS_);
    float a = g0[tid] * inv;
    la0[tid] = a; lb0[tid] = bt0[tid] - mean * a;
  } else if(tid < 128){
    int o = tid - 64;
    float mean = gstats1[o] * (1.0f / M_);
    float var  = gstats1[64 + o] * (1.0f / M_) - mean * mean;
    float inv  = 1.0f / sqrtf(var + EPS_);
    float a = g1[o] * inv;
    la1[o] = a; lb1[o] = bt1[o] - mean * a;
  }
  __syncthreads();

  const int m = blockIdx.x * 256 + tid;
  const int bs = m >> 5;

  // Phase A: L2 recompute, c-outer. acc2[o] = b1[o] + sum_c w1[o][c]*h1_c,
  // fma order per o identical to the o-outer/c-inner original.
  float acc2[64];
#pragma unroll
  for(int o = 0; o < 64; ++o) acc2[o] = b1[o];
  for(int c = 0; c < 64; ++c){
    float v = bf2f(y1[(size_t)c * M_ + m]);
    float h1c = fmaxf(la0[c] * v + lb0[c], 0.0f);
#pragma unroll
    for(int o = 0; o < 64; ++o) acc2[o] = fmaf(w1[o*64 + c], h1c, acc2[o]);
  }
#pragma unroll
  for(int o = 0; o < 64; ++o) acc2[o] = fmaxf(la1[o] * acc2[o] + lb1[o], 0.0f); // h2 in place

  // Phase B: L3 GEMM, o-outer, contiguous w2 reads; fused stats + k-max/min.
  const int col = tid & 31;
  for(int o = 0; o < 128; ++o){
    float acc = b2[o];
#pragma unroll
    for(int c = 0; c < 64; ++c) acc = fmaf(w2[o*64 + c], acc2[c], acc);
    atomicAdd(&sm_sum[o*33 + col], acc);
    atomicAdd(&sm_sq [o*33 + col], acc*acc);
    float mx = acc, mn = acc;
#pragma unroll
    for(int off = 1; off < 32; off <<= 1){       // stays within the 32-lane k-group
      mx = fmaxf(mx, __shfl_xor(mx, off, 64));
      mn = fminf(mn, __shfl_xor(mn, off, 64));
    }
    if((tid & 31) == 0){
      maxk[(size_t)bs * 128 + o] = mx;
      mink[(size_t)bs * 128 + o] = mn;
    }
  }
  __syncthreads();
  if(tid < 128){
    float s = 0.f;
#pragma unroll
    for(int c = 0; c < 32; ++c) s += sm_sum[tid*33 + c];
    atomicAdd(&gstats2[tid], s);
  } else {
    int o = tid - 128; float s = 0.f;
#pragma unroll
    for(int c = 0; c < 32; ++c) s += sm_sq[o*33 + c];
    atomicAdd(&gstats2[128 + o], s);
  }
}

// ---------------------------------------------------------------------------
// 6) Final: BN2+ReLU applied to max/min endpoints (max_k relu(a*v+b) =
//    max(relu(a*mx+b), relu(a*mn+b)) for either sign of a). Fully coalesced.
// ---------------------------------------------------------------------------
__global__ __launch_bounds__(256) void final_kernel(const float* __restrict__ maxk,
                                                    const float* __restrict__ mink,
                                                    const float* __restrict__ gstats2,
                                                    const float* __restrict__ g,
                                                    const float* __restrict__ bt,
                                                    float* __restrict__ out_np){
  const int gid = blockIdx.x * 256 + threadIdx.x;   // == bs*128 + o
  const int o = gid & 127;
  float mean = gstats2[o] * (1.0f / M_);
  float var  = gstats2[128 + o] * (1.0f / M_) - mean * mean;
  float inv  = 1.0f / sqrtf(var + EPS_);
  float a = g[o] * inv;
  float b = bt[o] - mean * a;
  float mx = maxk[gid], mn = mink[gid];
  out_np[gid] = fmaxf(fmaxf(a * mx + b, 0.0f), fmaxf(a * mn + b, 0.0f));
}

// ---------------------------------------------------------------------------
extern "C" void kernel_launch(void* const* d_in, const int* in_sizes, int n_in,
                              void* d_out, int out_size, void* d_ws, size_t ws_size,
                              hipStream_t stream){
  (void)in_sizes; (void)n_in; (void)out_size;
  const float* xyz = (const float*)d_in[0];
  const float* pts = (const float*)d_in[1];
  const float* w0 = (const float*)d_in[2];  const float* b0  = (const float*)d_in[3];
  const float* g0 = (const float*)d_in[4];  const float* bt0 = (const float*)d_in[5];
  const float* w1 = (const float*)d_in[6];  const float* b1  = (const float*)d_in[7];
  const float* g1 = (const float*)d_in[8];  const float* bt1 = (const float*)d_in[9];
  const float* w2 = (const float*)d_in[10]; const float* b2  = (const float*)d_in[11];
  const float* g2 = (const float*)d_in[12]; const float* bt2 = (const float*)d_in[13];

  float* out    = (float*)d_out;
  float* newxyz = out;                       // (B,S,3)
  float* newpts = out + (size_t)B_ * S_ * 3; // (B,S,128)

  // Workspace layout (total ~82.1 MB):
  const size_t off_gidx  = 0;
  const size_t off_stats = off_gidx  + (size_t)M_ * 4;
  const size_t off_maxk  = off_stats + 65536;
  const size_t off_mink  = off_maxk  + (size_t)NQ_ * 128 * 4;
  const size_t off_y1    = off_mink  + (size_t)NQ_ * 128 * 4;
  const size_t need      = off_y1    + (size_t)M_ * 64 * 2;
  if(ws_size < need) return;   // graceful failure instead of a device fault

  char* ws = (char*)d_ws;
  int*      gidx   = (int*)     (ws + off_gidx);
  float*    gstats = (float*)   (ws + off_stats);
  float*    maxk   = (float*)   (ws + off_maxk);
  float*    mink   = (float*)   (ws + off_mink);
  uint16_t* y1     = (uint16_t*)(ws + off_y1);

  zero_stats_kernel<<<2, 256, 0, stream>>>(gstats);
  fps_kernel  <<<B_, 256, 0, stream>>>(xyz, newxyz);
  ballq_kernel<<<NQ_ / 4, 256, 0, stream>>>(xyz, newxyz, gidx);

  layer1_kernel      <<<M_ / 256, 256, 0, stream>>>(xyz, pts, newxyz, gidx, w0, b0, y1, gstats);
  layer2_stats_kernel<<<M_ / 256, 256, 0, stream>>>(y1, gstats, g0, bt0, w1, b1, gstats + 128);
  layer3_kernel      <<<M_ / 256, 256, 0, stream>>>(y1, gstats, g0, bt0, w1, b1,
                                                    gstats + 128, g1, bt1, w2, b2,
                                                    gstats + 256, maxk, mink);
  final_kernel<<<(NQ_ * 128) / 256, 256, 0, stream>>>(maxk, mink, gstats + 256, g2, bt2, newpts);
}

// Round 8
// 1489.181 us; speedup vs baseline: 2.7773x; 1.6271x over previous
//
#include <hip/hip_runtime.h>
#include <stdint.h>

#define B_ 16
#define N_ 4096
#define D_ 64
#define S_ 1024
#define K_ 32
#define M_ (B_*S_*K_)   /* 524288 */
#define NQ_ (B_*S_)     /* 16384 */
#define EPS_ 1e-5f
#define WPAD 72         /* bf16 LDS row stride: 72*2=144 B, 16B-aligned frags */

typedef short bf16x8 __attribute__((ext_vector_type(8)));
typedef float f32x4  __attribute__((ext_vector_type(4)));

static __device__ __forceinline__ float bf2f(uint16_t u){
  union{uint32_t i; float f;} v; v.i = ((uint32_t)u) << 16; return v.f;
}
static __device__ __forceinline__ uint16_t f2bf(float f){
  union{uint32_t i; float f;} v; v.f = f;
  uint32_t u = v.i;
  uint32_t r = (u + 0x7FFFu + ((u >> 16) & 1u)) >> 16;   // RNE, finite inputs
  return (uint16_t)r;
}

// Build an MFMA A-fragment of h1 = relu(la0*y1 + lb0) in bf16 from y1t[m][c].
// Lane layout (16x16x32 bf16 A): m = lane&15 (+tile), k(c) = (lane>>4)*8 + j.
static __device__ __forceinline__ bf16x8 h1_frag(const uint16_t* __restrict__ y1t,
                                                 const float* la0s, const float* lb0s,
                                                 int m, int kb){
  const uint4 raw = *(const uint4*)(y1t + (size_t)m * 64 + kb);
  uint32_t wrd[4] = {raw.x, raw.y, raw.z, raw.w};
  bf16x8 f;
#pragma unroll
  for(int i = 0; i < 4; ++i){
    int c0 = kb + 2*i;
    float v0 = bf2f((uint16_t)(wrd[i] & 0xFFFFu));
    float v1 = bf2f((uint16_t)(wrd[i] >> 16));
    float h0 = fmaxf(la0s[c0]   * v0 + lb0s[c0],   0.0f);
    float h1 = fmaxf(la0s[c0+1] * v1 + lb0s[c0+1], 0.0f);
    f[2*i]   = (short)f2bf(h0);
    f[2*i+1] = (short)f2bf(h1);
  }
  return f;
}

// ---------------------------------------------------------------------------
// 0) Zero the global stats accumulators (ws is poisoned 0xAA before launch).
// ---------------------------------------------------------------------------
__global__ __launch_bounds__(256) void zero_stats_kernel(float* __restrict__ s){
  s[blockIdx.x * 256 + threadIdx.x] = 0.0f;   // grid 2 -> 512 floats
}

// ---------------------------------------------------------------------------
// 1) FPS: one block/batch, 256 threads, 16 pts/thread. u64-key argmax,
//    one barrier/iter. Bit-identical decisions to verified rounds 3-7.
// ---------------------------------------------------------------------------
__global__ __launch_bounds__(256) void fps_kernel(const float* __restrict__ xyz,
                                                  float* __restrict__ out_newxyz){
  const int b = blockIdx.x;
  const int tid = threadIdx.x;
  const float* X = xyz + (size_t)b * N_ * 3;
  __shared__ float4 sxyz[N_];
  __shared__ unsigned long long slots[2][4];
  float px[16], py[16], pz[16], dist[16];
#pragma unroll
  for(int t = 0; t < 16; ++t){
    int p = tid + t * 256;
    px[t] = X[p*3 + 0]; py[t] = X[p*3 + 1]; pz[t] = X[p*3 + 2];
    dist[t] = 1e10f;
    sxyz[p] = make_float4(px[t], py[t], pz[t], 0.0f);
  }
  __syncthreads();
  int far = 0;
  for(int it = 0; it < S_; ++it){
    float4 c = sxyz[far];
    if(tid == 0){
      float* o = out_newxyz + ((size_t)b * S_ + it) * 3;
      o[0] = c.x; o[1] = c.y; o[2] = c.z;
    }
    if(it == S_ - 1) break;
    float bestd = -1.0f; int bestp = 0;
#pragma unroll
    for(int t = 0; t < 16; ++t){
      float d;
      {
#pragma clang fp contract(off)
        float dx = px[t] - c.x, dy = py[t] - c.y, dz = pz[t] - c.z;
        d = dx*dx + dy*dy + dz*dz;
      }
      float nd = fminf(dist[t], d);
      dist[t] = nd;
      if(nd > bestd){ bestd = nd; bestp = tid + t*256; }
    }
    unsigned long long key = ((unsigned long long)__float_as_uint(bestd) << 32)
                           | (unsigned long long)(uint32_t)(~bestp);
#pragma unroll
    for(int off = 1; off < 64; off <<= 1){
      unsigned long long ok = __shfl_xor(key, off, 64);
      if(ok > key) key = ok;
    }
    const int par = it & 1;
    if((tid & 63) == 0) slots[par][tid >> 6] = key;
    __syncthreads();
    unsigned long long bk = slots[par][0];
#pragma unroll
    for(int w = 1; w < 4; ++w){
      unsigned long long ok = slots[par][w];
      if(ok > bk) bk = ok;
    }
    far = (int)(~(uint32_t)bk);
  }
}

// ---------------------------------------------------------------------------
// 2) Ball query: FP64 sq, bit-identical to numpy float64 ref (verified r3).
// ---------------------------------------------------------------------------
__global__ __launch_bounds__(256) void ballq_kernel(const float* __restrict__ xyz,
                                                    const float* __restrict__ newxyz,
                                                    int* __restrict__ gidx){
  const int wslot = threadIdx.x >> 6;
  const int lane  = threadIdx.x & 63;
  const int q = blockIdx.x * 4 + wslot;
  const int b = q >> 10;
  const float* X = xyz + (size_t)b * N_ * 3;
  const double R2D = 0.2 * 0.2;
  double nx, ny, nz, sa;
  {
    const float* NP = newxyz + (size_t)q * 3;
    nx = (double)NP[0]; ny = (double)NP[1]; nz = (double)NP[2];
    sa = nx*nx + ny*ny + nz*nz;
  }
  __shared__ int sidx[4][K_];
  int count = 0;
  for(int base = 0; base < N_; base += 64){
    int p = base + lane;
    double pxv = (double)X[p*3 + 0], pyv = (double)X[p*3 + 1], pzv = (double)X[p*3 + 2];
    double sb = pxv*pxv + pyv*pyv + pzv*pzv;
    double dt = nx*pxv + ny*pyv + nz*pzv;
    double sq = sa + sb - 2.0 * dt;
    bool inb = !(sq > R2D);
    unsigned long long mask = __ballot(inb);
    int pos = count + __popcll(mask & ((1ull << lane) - 1ull));
    if(inb && pos < K_) sidx[wslot][pos] = p;
    count += (int)__popcll(mask);
    if(count >= K_) break;
  }
  __syncthreads();
  int nvalid = count < K_ ? count : K_;
  if(lane < K_){
    int first = sidx[wslot][0];
    int v = (lane < nvalid) ? sidx[wslot][lane] : first;
    gidx[(size_t)q * K_ + lane] = v;
  }
}

// ---------------------------------------------------------------------------
// 3) Layer 1: gather + concat + GEMM (67->64) + bias. NOW writes y1
//    TRANSPOSED: y1t[m][c] (row stride 64) so MFMA A-frags are direct 16B
//    loads downstream. Values identical to previous rounds; fused stats0.
// ---------------------------------------------------------------------------
__global__ __launch_bounds__(256)
void layer1_kernel(const float* __restrict__ xyz,
                   const float* __restrict__ pts,
                   const float* __restrict__ newxyz,
                   const int* __restrict__ gidx,
                   const float* __restrict__ w,
                   const float* __restrict__ bias,
                   uint16_t* __restrict__ y1t,
                   float* __restrict__ gstats){
  __shared__ float sm_sum[64*33];
  __shared__ float sm_sq [64*33];
  const int tid = threadIdx.x;
  for(int i = tid; i < 64*33; i += 256){ sm_sum[i] = 0.f; sm_sq[i] = 0.f; }
  __syncthreads();

  const int m = blockIdx.x * 256 + tid;
  const int bs = m >> 5;
  const int b  = bs >> 10;
  const int j  = gidx[m];
  float x[67];
  {
    const float* nxp = newxyz + (size_t)bs * 3;
    const float* pp  = xyz + ((size_t)b * N_ + j) * 3;
    x[0] = pp[0] - nxp[0]; x[1] = pp[1] - nxp[1]; x[2] = pp[2] - nxp[2];
  }
  {
    const float4* pr = (const float4*)(pts + ((size_t)b * N_ + j) * D_);
#pragma unroll
    for(int c4 = 0; c4 < 16; ++c4){
      float4 v = pr[c4];
      x[3 + c4*4 + 0] = v.x; x[3 + c4*4 + 1] = v.y;
      x[3 + c4*4 + 2] = v.z; x[3 + c4*4 + 3] = v.w;
    }
  }
  const int col = tid & 31;
  for(int o = 0; o < 64; ++o){
    float acc = bias[o];
#pragma unroll
    for(int c = 0; c < 67; ++c) acc = fmaf(w[o*67 + c], x[c], acc);
    y1t[(size_t)m * 64 + o] = f2bf(acc);
    atomicAdd(&sm_sum[o*33 + col], acc);
    atomicAdd(&sm_sq [o*33 + col], acc*acc);
  }
  __syncthreads();
  if(tid < 64){
    float s = 0.f;
#pragma unroll
    for(int c = 0; c < 32; ++c) s += sm_sum[tid*33 + c];
    atomicAdd(&gstats[tid], s);
  } else if(tid < 128){
    int o = tid - 64; float s = 0.f;
#pragma unroll
    for(int c = 0; c < 32; ++c) s += sm_sq[o*33 + c];
    atomicAdd(&gstats[64 + o], s);
  }
}

// ---------------------------------------------------------------------------
// 4) Layer 2 stats via MFMA. Wave = 32 m-rows; z2 = mfma(h1,w1b)+b1, stats1
//    accumulated (pre-BN, matching reference). Same mfma order as layer3's
//    recompute => bitwise-identical z2.
// ---------------------------------------------------------------------------
__global__ __launch_bounds__(256)
void layer2_stats_kernel(const uint16_t* __restrict__ y1t,
                         const float* __restrict__ gstats0,
                         const float* __restrict__ g0,
                         const float* __restrict__ bt0,
                         const float* __restrict__ w1,
                         const float* __restrict__ b1,
                         float* __restrict__ gstats1){
  __shared__ short w1b[64*WPAD];
  __shared__ float la0s[64], lb0s[64], b1s[64];
  __shared__ float ssum[64], ssq[64];
  const int tid = threadIdx.x;
#pragma unroll
  for(int i = 0; i < 16; ++i){
    int e = i*256 + tid;                       // 4096 weights
    w1b[(e>>6)*WPAD + (e&63)] = (short)f2bf(w1[e]);
  }
  if(tid < 64){
    float mean = gstats0[tid] * (1.0f / M_);
    float var  = gstats0[64 + tid] * (1.0f / M_) - mean * mean;
    float inv  = 1.0f / sqrtf(var + EPS_);
    float a = g0[tid] * inv;
    la0s[tid] = a; lb0s[tid] = bt0[tid] - mean * a;
    b1s[tid] = b1[tid];
  } else if(tid < 128){
    ssum[tid-64] = 0.f; ssq[tid-64] = 0.f;
  }
  __syncthreads();

  const int wave = tid >> 6, lane = tid & 63;
  const int row = lane & 15, quad = lane >> 4;
  const int wm0 = blockIdx.x * 128 + wave * 32;

  bf16x8 afr[2][2];
#pragma unroll
  for(int s = 0; s < 2; ++s)
#pragma unroll
    for(int k2 = 0; k2 < 2; ++k2)
      afr[s][k2] = h1_frag(y1t, la0s, lb0s, wm0 + s*16 + row, quad*8 + k2*32);

  for(int ot = 0; ot < 4; ++ot){
    bf16x8 bfr0 = *(const bf16x8*)&w1b[(ot*16 + row)*WPAD + quad*8];
    bf16x8 bfr1 = *(const bf16x8*)&w1b[(ot*16 + row)*WPAD + quad*8 + 32];
    const float bb = b1s[ot*16 + row];
    float sum_ = 0.f, sq_ = 0.f;
#pragma unroll
    for(int s = 0; s < 2; ++s){
      f32x4 acc = {0.f, 0.f, 0.f, 0.f};
      acc = __builtin_amdgcn_mfma_f32_16x16x32_bf16(afr[s][0], bfr0, acc, 0, 0, 0);
      acc = __builtin_amdgcn_mfma_f32_16x16x32_bf16(afr[s][1], bfr1, acc, 0, 0, 0);
#pragma unroll
      for(int r = 0; r < 4; ++r){
        float z = acc[r] + bb;
        sum_ += z; sq_ = fmaf(z, z, sq_);
      }
    }
    sum_ += __shfl_xor(sum_, 16, 64); sum_ += __shfl_xor(sum_, 32, 64);
    sq_  += __shfl_xor(sq_,  16, 64); sq_  += __shfl_xor(sq_,  32, 64);
    if(quad == 0){
      atomicAdd(&ssum[ot*16 + row], sum_);
      atomicAdd(&ssq [ot*16 + row], sq_);
    }
  }
  __syncthreads();
  if(tid < 64)       atomicAdd(&gstats1[tid], ssum[tid]);
  else if(tid < 128) atomicAdd(&gstats1[tid], ssq[tid - 64]);
}

// ---------------------------------------------------------------------------
// 5) Layer 3 via MFMA. Recompute z2 (identical mfma order), BN1+ReLU ->
//    h2 bf16 staged per-wave in LDS, L3 GEMM o-tile-at-a-time with immediate
//    epilogue (stats2 + max/min over the wave's 32-m k-group).
// ---------------------------------------------------------------------------
__global__ __launch_bounds__(256)
void layer3_kernel(const uint16_t* __restrict__ y1t,
                   const float* __restrict__ gstats0,
                   const float* __restrict__ g0,
                   const float* __restrict__ bt0,
                   const float* __restrict__ w1,
                   const float* __restrict__ b1,
                   const float* __restrict__ gstats1,
                   const float* __restrict__ g1,
                   const float* __restrict__ bt1,
                   const float* __restrict__ w2,
                   const float* __restrict__ b2,
                   float* __restrict__ gstats2,
                   float* __restrict__ maxk,
                   float* __restrict__ mink){
  __shared__ short w1b[64*WPAD];
  __shared__ short w2b[128*WPAD];
  __shared__ short h2s[4][32*WPAD];
  __shared__ float la0s[64], lb0s[64], la1s[64], lb1s[64], b1s[64], b2s[128];
  __shared__ float ssum[128], ssq[128];
  const int tid = threadIdx.x;
#pragma unroll
  for(int i = 0; i < 16; ++i){
    int e = i*256 + tid;
    w1b[(e>>6)*WPAD + (e&63)] = (short)f2bf(w1[e]);
  }
#pragma unroll
  for(int i = 0; i < 32; ++i){
    int e = i*256 + tid;                       // 8192 weights
    w2b[(e>>6)*WPAD + (e&63)] = (short)f2bf(w2[e]);
  }
  if(tid < 64){
    float mean = gstats0[tid] * (1.0f / M_);
    float var  = gstats0[64 + tid] * (1.0f / M_) - mean * mean;
    float inv  = 1.0f / sqrtf(var + EPS_);
    float a = g0[tid] * inv;
    la0s[tid] = a; lb0s[tid] = bt0[tid] - mean * a;
    b1s[tid] = b1[tid];
  } else if(tid < 128){
    int o = tid - 64;
    float mean = gstats1[o] * (1.0f / M_);
    float var  = gstats1[64 + o] * (1.0f / M_) - mean * mean;
    float inv  = 1.0f / sqrtf(var + EPS_);
    float a = g1[o] * inv;
    la1s[o] = a; lb1s[o] = bt1[o] - mean * a;
  }
  if(tid < 128){ b2s[tid] = b2[tid]; ssum[tid] = 0.f; }
  else         { ssq[tid - 128] = 0.f; }
  __syncthreads();

  const int wave = tid >> 6, lane = tid & 63;
  const int row = lane & 15, quad = lane >> 4;
  const int wm0 = blockIdx.x * 128 + wave * 32;
  short* h2w = &h2s[wave][0];

  // ---- L2 recompute (same order as layer2_stats) + BN1 + ReLU -> h2 LDS
  {
    bf16x8 afr[2][2];
#pragma unroll
    for(int s = 0; s < 2; ++s)
#pragma unroll
      for(int k2 = 0; k2 < 2; ++k2)
        afr[s][k2] = h1_frag(y1t, la0s, lb0s, wm0 + s*16 + row, quad*8 + k2*32);

    for(int ot = 0; ot < 4; ++ot){
      bf16x8 bfr0 = *(const bf16x8*)&w1b[(ot*16 + row)*WPAD + quad*8];
      bf16x8 bfr1 = *(const bf16x8*)&w1b[(ot*16 + row)*WPAD + quad*8 + 32];
      const int o = ot*16 + row;
      const float bb = b1s[o], a1 = la1s[o], c1 = lb1s[o];
#pragma unroll
      for(int s = 0; s < 2; ++s){
        f32x4 acc = {0.f, 0.f, 0.f, 0.f};
        acc = __builtin_amdgcn_mfma_f32_16x16x32_bf16(afr[s][0], bfr0, acc, 0, 0, 0);
        acc = __builtin_amdgcn_mfma_f32_16x16x32_bf16(afr[s][1], bfr1, acc, 0, 0, 0);
#pragma unroll
        for(int r = 0; r < 4; ++r){
          float z = acc[r] + bb;
          float h = fmaxf(a1 * z + c1, 0.0f);
          int ml = s*16 + quad*4 + r;                 // C-layout row
          h2w[ml*WPAD + o] = (short)f2bf(h);          // col = o
        }
      }
    }
  }
  // ---- L3 GEMM: A = h2 (from this wave's LDS region; wave-internal dep)
  {
    bf16x8 hfr[2][2];
#pragma unroll
    for(int s = 0; s < 2; ++s)
#pragma unroll
      for(int k2 = 0; k2 < 2; ++k2)
        hfr[s][k2] = *(const bf16x8*)&h2w[(s*16 + row)*WPAD + quad*8 + k2*32];

    for(int ot = 0; ot < 8; ++ot){
      bf16x8 bfr0 = *(const bf16x8*)&w2b[(ot*16 + row)*WPAD + quad*8];
      bf16x8 bfr1 = *(const bf16x8*)&w2b[(ot*16 + row)*WPAD + quad*8 + 32];
      const int o = ot*16 + row;
      const float bb = b2s[o];
      float sum_ = 0.f, sq_ = 0.f, mx = -1e30f, mn = 1e30f;
#pragma unroll
      for(int s = 0; s < 2; ++s){
        f32x4 acc = {0.f, 0.f, 0.f, 0.f};
        acc = __builtin_amdgcn_mfma_f32_16x16x32_bf16(hfr[s][0], bfr0, acc, 0, 0, 0);
        acc = __builtin_amdgcn_mfma_f32_16x16x32_bf16(hfr[s][1], bfr1, acc, 0, 0, 0);
#pragma unroll
        for(int r = 0; r < 4; ++r){
          float z = acc[r] + bb;
          sum_ += z; sq_ = fmaf(z, z, sq_);
          mx = fmaxf(mx, z); mn = fminf(mn, z);
        }
      }
      sum_ += __shfl_xor(sum_, 16, 64); sum_ += __shfl_xor(sum_, 32, 64);
      sq_  += __shfl_xor(sq_,  16, 64); sq_  += __shfl_xor(sq_,  32, 64);
      mx = fmaxf(mx, __shfl_xor(mx, 16, 64)); mx = fmaxf(mx, __shfl_xor(mx, 32, 64));
      mn = fminf(mn, __shfl_xor(mn, 16, 64)); mn = fminf(mn, __shfl_xor(mn, 32, 64));
      if(quad == 0){
        atomicAdd(&ssum[o], sum_);
        atomicAdd(&ssq [o], sq_);
        maxk[(size_t)(wm0 >> 5) * 128 + o] = mx;     // wave's 32 m == one k-group
        mink[(size_t)(wm0 >> 5) * 128 + o] = mn;
      }
    }
  }
  __syncthreads();
  if(tid < 128) atomicAdd(&gstats2[tid], ssum[tid]);
  else          atomicAdd(&gstats2[tid], ssq[tid - 128]);
}

// ---------------------------------------------------------------------------
// 6) Final: BN2+ReLU on max/min endpoints. Unchanged.
// ---------------------------------------------------------------------------
__global__ __launch_bounds__(256) void final_kernel(const float* __restrict__ maxk,
                                                    const float* __restrict__ mink,
                                                    const float* __restrict__ gstats2,
                                                    const float* __restrict__ g,
                                                    const float* __restrict__ bt,
                                                    float* __restrict__ out_np){
  const int gid = blockIdx.x * 256 + threadIdx.x;
  const int o = gid & 127;
  float mean = gstats2[o] * (1.0f / M_);
  float var  = gstats2[128 + o] * (1.0f / M_) - mean * mean;
  float inv  = 1.0f / sqrtf(var + EPS_);
  float a = g[o] * inv;
  float b = bt[o] - mean * a;
  float mx = maxk[gid], mn = mink[gid];
  out_np[gid] = fmaxf(fmaxf(a * mx + b, 0.0f), fmaxf(a * mn + b, 0.0f));
}

// ---------------------------------------------------------------------------
extern "C" void kernel_launch(void* const* d_in, const int* in_sizes, int n_in,
                              void* d_out, int out_size, void* d_ws, size_t ws_size,
                              hipStream_t stream){
  (void)in_sizes; (void)n_in; (void)out_size;
  const float* xyz = (const float*)d_in[0];
  const float* pts = (const float*)d_in[1];
  const float* w0 = (const float*)d_in[2];  const float* b0  = (const float*)d_in[3];
  const float* g0 = (const float*)d_in[4];  const float* bt0 = (const float*)d_in[5];
  const float* w1 = (const float*)d_in[6];  const float* b1  = (const float*)d_in[7];
  const float* g1 = (const float*)d_in[8];  const float* bt1 = (const float*)d_in[9];
  const float* w2 = (const float*)d_in[10]; const float* b2  = (const float*)d_in[11];
  const float* g2 = (const float*)d_in[12]; const float* bt2 = (const float*)d_in[13];

  float* out    = (float*)d_out;
  float* newxyz = out;                       // (B,S,3)
  float* newpts = out + (size_t)B_ * S_ * 3; // (B,S,128)

  const size_t off_gidx  = 0;
  const size_t off_stats = off_gidx  + (size_t)M_ * 4;
  const size_t off_maxk  = off_stats + 65536;
  const size_t off_mink  = off_maxk  + (size_t)NQ_ * 128 * 4;
  const size_t off_y1    = off_mink  + (size_t)NQ_ * 128 * 4;
  const size_t need      = off_y1    + (size_t)M_ * 64 * 2;
  if(ws_size < need) return;

  char* ws = (char*)d_ws;
  int*      gidx   = (int*)     (ws + off_gidx);
  float*    gstats = (float*)   (ws + off_stats);
  float*    maxk   = (float*)   (ws + off_maxk);
  float*    mink   = (float*)   (ws + off_mink);
  uint16_t* y1t    = (uint16_t*)(ws + off_y1);

  zero_stats_kernel<<<2, 256, 0, stream>>>(gstats);
  fps_kernel  <<<B_, 256, 0, stream>>>(xyz, newxyz);
  ballq_kernel<<<NQ_ / 4, 256, 0, stream>>>(xyz, newxyz, gidx);

  layer1_kernel      <<<M_ / 256, 256, 0, stream>>>(xyz, pts, newxyz, gidx, w0, b0, y1t, gstats);
  layer2_stats_kernel<<<M_ / 128, 256, 0, stream>>>(y1t, gstats, g0, bt0, w1, b1, gstats + 128);
  layer3_kernel      <<<M_ / 128, 256, 0, stream>>>(y1t, gstats, g0, bt0, w1, b1,
                                                    gstats + 128, g1, bt1, w2, b2,
                                                    gstats + 256, maxk, mink);
  final_kernel<<<(NQ_ * 128) / 256, 256, 0, stream>>>(maxk, mink, gstats + 256, g2, bt2, newpts);
}